// Round 1
// baseline (501.923 us; speedup 1.0000x reference)
//
#include <hip/hip_runtime.h>
#include <hip/hip_bf16.h>
#include <math.h>

#define BATCH 4
#define SEQ 2049
#define DIMD 256
#define NHEAD 4
#define DH 64
#define WIN 64
#define M_ROWS (BATCH * SEQ) // 8196

typedef __attribute__((ext_vector_type(8))) short short8;
typedef __attribute__((ext_vector_type(4))) float f32x4;
typedef __hip_bfloat16 bf16;

__device__ __forceinline__ float b2f(short u) {
    union { unsigned int i; float f; } c;
    c.i = ((unsigned int)(unsigned short)u) << 16;
    return c.f;
}

// ---------------- weight fp32 -> bf16 conversion (all 4 weights, one kernel) ----------------
__global__ __launch_bounds__(256) void cvt_weights(
        const float* __restrict__ wq, const float* __restrict__ wo,
        const float* __restrict__ w1, const float* __restrict__ w2,
        bf16* __restrict__ oq, bf16* __restrict__ oo,
        bf16* __restrict__ o1, bf16* __restrict__ o2) {
    int i = blockIdx.x * 256 + threadIdx.x;
    if (i < 196608)      oq[i]          = __float2bfloat16(wq[i]);
    else if (i < 262144) oo[i - 196608] = __float2bfloat16(wo[i - 196608]);
    else if (i < 393216) o1[i - 262144] = __float2bfloat16(w1[i - 262144]);
    else                 o2[i - 393216] = __float2bfloat16(w2[i - 393216]);
}

// ---------------- RMSNorm: fp32 in -> bf16 out (1 wave per 256-elem row) ----------------
__global__ __launch_bounds__(256) void rmsnorm_kernel(const float* __restrict__ x,
        const float* __restrict__ w, bf16* __restrict__ h, int M) {
    int wid = threadIdx.x >> 6, lane = threadIdx.x & 63;
    int row = blockIdx.x * 4 + wid;
    if (row >= M) return;
    const float4 v = reinterpret_cast<const float4*>(x + (size_t)row * DIMD)[lane];
    float ss = v.x * v.x + v.y * v.y + v.z * v.z + v.w * v.w;
    #pragma unroll
    for (int o = 1; o < 64; o <<= 1) ss += __shfl_xor(ss, o, 64);
    float r = rsqrtf(ss * (1.0f / DIMD) + 1e-6f);
    const float4 wv = reinterpret_cast<const float4*>(w)[lane];
    bf16* hp = h + (size_t)row * DIMD + lane * 4;
    hp[0] = __float2bfloat16(v.x * r * wv.x);
    hp[1] = __float2bfloat16(v.y * r * wv.y);
    hp[2] = __float2bfloat16(v.z * r * wv.z);
    hp[3] = __float2bfloat16(v.w * r * wv.w);
}

// ---------------- GEMM C = A * B^T (+bias, epilogue) ----------------
// A [M,K] bf16 row-major, B [N,K] bf16 row-major (= weight as given).
// MODE 0: store bf16(acc+bias). MODE 1: store f32(acc+bias+resid). MODE 2: store bf16(gelu(acc+bias)).
// Block: 256 thr = 4 waves (2x2), each wave 64x64 output via 4x4 mfma_16x16x32 frags.
template<int MODE>
__global__ __launch_bounds__(256) void gemm_bt(
        const bf16* __restrict__ A, const bf16* __restrict__ B,
        const float* __restrict__ bias, const float* __restrict__ resid,
        void* __restrict__ C, int M, int N, int K) {
    int lane = threadIdx.x & 63, wid = threadIdx.x >> 6;
    int m0 = blockIdx.x * 128 + (wid >> 1) * 64;
    int n0 = blockIdx.y * 128 + (wid & 1) * 64;
    int lrow = lane & 15;
    int koff = (lane >> 4) * 8;
    f32x4 acc[4][4];
    #pragma unroll
    for (int i = 0; i < 4; i++)
        #pragma unroll
        for (int j = 0; j < 4; j++) acc[i][j] = (f32x4){0.f, 0.f, 0.f, 0.f};

    for (int k0 = 0; k0 < K; k0 += 32) {
        short8 a[4], b[4];
        #pragma unroll
        for (int mi = 0; mi < 4; mi++) {
            int row = m0 + mi * 16 + lrow;
            if (row > M - 1) row = M - 1; // clamp tail loads (stores guarded)
            a[mi] = *reinterpret_cast<const short8*>(A + (size_t)row * K + k0 + koff);
        }
        #pragma unroll
        for (int ni = 0; ni < 4; ni++) {
            int col = n0 + ni * 16 + lrow;
            b[ni] = *reinterpret_cast<const short8*>(B + (size_t)col * K + k0 + koff);
        }
        #pragma unroll
        for (int mi = 0; mi < 4; mi++)
            #pragma unroll
            for (int ni = 0; ni < 4; ni++)
                acc[mi][ni] = __builtin_amdgcn_mfma_f32_16x16x32_bf16(a[mi], b[ni], acc[mi][ni], 0, 0, 0);
    }

    int c0 = lane & 15, r0 = (lane >> 4) * 4;
    #pragma unroll
    for (int mi = 0; mi < 4; mi++) {
        #pragma unroll
        for (int ni = 0; ni < 4; ni++) {
            int col = n0 + ni * 16 + c0;
            float bv = bias[col];
            #pragma unroll
            for (int j = 0; j < 4; j++) {
                int row = m0 + mi * 16 + r0 + j;
                if (row < M) {
                    float v = acc[mi][ni][j] + bv;
                    if (MODE == 2) v = 0.5f * v * (1.0f + erff(v * 0.70710678118654752f));
                    if (MODE == 1) {
                        v += resid[(size_t)row * N + col];
                        reinterpret_cast<float*>(C)[(size_t)row * N + col] = v;
                    } else {
                        reinterpret_cast<bf16*>(C)[(size_t)row * N + col] = __float2bfloat16(v);
                    }
                }
            }
        }
    }
}

// ---------------- banded attention, queries q>=1 (1 wave per (b,h,q)) ----------------
// keys: j=0 (global) + band [max(0,q-64), min(S-1,q+64)]  (<=130 keys)
__global__ __launch_bounds__(256) void attn_band(const bf16* __restrict__ qkv, bf16* __restrict__ ctx) {
    __shared__ float q_s[4][64];
    __shared__ float p_s[4][136];
    int wid = threadIdx.x >> 6, lane = threadIdx.x & 63;
    int gw = blockIdx.x * 4 + wid;          // 0 .. B*H*(S-1)-1 = 32767
    int q = 1 + (gw % (SEQ - 1));
    int bh = gw / (SEQ - 1);
    int b = bh >> 2, h = bh & 3;
    size_t rowq = (size_t)(b * SEQ + q);
    q_s[wid][lane] = __bfloat162float(qkv[rowq * 768 + h * 64 + lane]);
    __syncthreads();

    int jstart = q - WIN; if (jstart < 0) jstart = 0;
    int jend = q + WIN;   if (jend > SEQ - 1) jend = SEQ - 1;
    int extra = (jstart > 0) ? 1 : 0;
    int nk = jend - jstart + 1 + extra;

    float mx = -1e30f;
    for (int t = lane; t < nk; t += 64) {
        int j = (extra && t == 0) ? 0 : (jstart + t - extra);
        const short8* kp = reinterpret_cast<const short8*>(qkv + ((size_t)(b * SEQ + j)) * 768 + 256 + h * 64);
        float s = 0.f;
        #pragma unroll
        for (int d8 = 0; d8 < 8; ++d8) {
            short8 kv = kp[d8];
            #pragma unroll
            for (int e = 0; e < 8; ++e) s += q_s[wid][d8 * 8 + e] * b2f(kv[e]);
        }
        s *= 0.125f;
        p_s[wid][t] = s;
        mx = fmaxf(mx, s);
    }
    #pragma unroll
    for (int o = 1; o < 64; o <<= 1) mx = fmaxf(mx, __shfl_xor(mx, o, 64));
    float sum = 0.f;
    for (int t = lane; t < nk; t += 64) {
        float p = expf(p_s[wid][t] - mx);
        p_s[wid][t] = p;
        sum += p;
    }
    #pragma unroll
    for (int o = 1; o < 64; o <<= 1) sum += __shfl_xor(sum, o, 64);

    float o_acc = 0.f;
    for (int t = 0; t < nk; ++t) {
        int j = (extra && t == 0) ? 0 : (jstart + t - extra);
        o_acc += p_s[wid][t] * __bfloat162float(qkv[((size_t)(b * SEQ + j)) * 768 + 512 + h * 64 + lane]);
    }
    ctx[rowq * 256 + h * 64 + lane] = __float2bfloat16(o_acc / sum);
}

// ---------------- global row q==0 (full attention over all S keys), 1 block per (b,h) ----------------
__global__ __launch_bounds__(256) void attn_global(const bf16* __restrict__ qkv, bf16* __restrict__ ctx) {
    __shared__ float q_s[64];
    __shared__ float p_s[SEQ];
    __shared__ float redm[4], reds[4], osum[4][64];
    int tid = threadIdx.x, lane = tid & 63, wid = tid >> 6;
    int b = blockIdx.x >> 2, h = blockIdx.x & 3;
    const size_t base = (size_t)b * SEQ;
    if (tid < 64) q_s[tid] = __bfloat162float(qkv[base * 768 + h * 64 + tid]);
    __syncthreads();
    float mx = -1e30f;
    for (int j = tid; j < SEQ; j += 256) {
        const short8* kp = reinterpret_cast<const short8*>(qkv + (base + j) * 768 + 256 + h * 64);
        float s = 0.f;
        #pragma unroll
        for (int d8 = 0; d8 < 8; ++d8) {
            short8 kv = kp[d8];
            #pragma unroll
            for (int e = 0; e < 8; ++e) s += q_s[d8 * 8 + e] * b2f(kv[e]);
        }
        s *= 0.125f;
        p_s[j] = s;
        mx = fmaxf(mx, s);
    }
    #pragma unroll
    for (int o = 1; o < 64; o <<= 1) mx = fmaxf(mx, __shfl_xor(mx, o, 64));
    if (lane == 0) redm[wid] = mx;
    __syncthreads();
    mx = fmaxf(fmaxf(redm[0], redm[1]), fmaxf(redm[2], redm[3]));
    float sum = 0.f;
    for (int j = tid; j < SEQ; j += 256) {
        float p = expf(p_s[j] - mx);
        p_s[j] = p;
        sum += p;
    }
    #pragma unroll
    for (int o = 1; o < 64; o <<= 1) sum += __shfl_xor(sum, o, 64);
    if (lane == 0) reds[wid] = sum;
    __syncthreads();
    sum = reds[0] + reds[1] + reds[2] + reds[3];
    float o_acc = 0.f;
    for (int j = wid; j < SEQ; j += 4)
        o_acc += p_s[j] * __bfloat162float(qkv[(base + j) * 768 + 512 + h * 64 + lane]);
    osum[wid][lane] = o_acc;
    __syncthreads();
    if (wid == 0) {
        float o = osum[0][lane] + osum[1][lane] + osum[2][lane] + osum[3][lane];
        ctx[base * 256 + h * 64 + lane] = __float2bfloat16(o / sum);
    }
}

extern "C" void kernel_launch(void* const* d_in, const int* in_sizes, int n_in,
                              void* d_out, int out_size, void* d_ws, size_t ws_size,
                              hipStream_t stream) {
    const float* x         = (const float*)d_in[0];
    const float* norm1_w   = (const float*)d_in[1];
    const float* in_proj_w = (const float*)d_in[2];
    const float* in_proj_b = (const float*)d_in[3];
    const float* out_proj_w= (const float*)d_in[4];
    const float* out_proj_b= (const float*)d_in[5];
    const float* norm2_w   = (const float*)d_in[6];
    const float* w1        = (const float*)d_in[7];
    const float* b1        = (const float*)d_in[8];
    const float* w2        = (const float*)d_in[9];
    const float* b2        = (const float*)d_in[10];
    float* out = (float*)d_out;

    const int M = M_ROWS; // 8196
    char* ws = (char*)d_ws;
    size_t off = 0;
    auto take = [&](size_t bytes) {
        char* p = ws + off;
        off = (off + bytes + 255) & ~(size_t)255;
        return p;
    };
    bf16* h_bf   = (bf16*)take((size_t)M * 256 * 2);
    bf16* qkv_bf = (bf16*)take((size_t)M * 768 * 2);
    bf16* ctx_bf = (bf16*)take((size_t)M * 256 * 2);
    float* x1    = (float*)take((size_t)M * 256 * 4);
    bf16* h2_bf  = (bf16*)take((size_t)M * 256 * 2);
    bf16* g_bf   = (bf16*)take((size_t)M * 512 * 2);
    bf16* wq_bf  = (bf16*)take(768 * 256 * 2);
    bf16* wo_bf  = (bf16*)take(256 * 256 * 2);
    bf16* w1_bf  = (bf16*)take(512 * 256 * 2);
    bf16* w2_bf  = (bf16*)take(256 * 512 * 2);
    (void)ws_size; (void)in_sizes; (void)n_in; (void)out_size;

    cvt_weights<<<dim3(2048), dim3(256), 0, stream>>>(in_proj_w, out_proj_w, w1, w2,
                                                      wq_bf, wo_bf, w1_bf, w2_bf);
    rmsnorm_kernel<<<dim3((M + 3) / 4), dim3(256), 0, stream>>>(x, norm1_w, h_bf, M);
    gemm_bt<0><<<dim3(65, 6), dim3(256), 0, stream>>>(h_bf, wq_bf, in_proj_b, (const float*)nullptr,
                                                      (void*)qkv_bf, M, 768, 256);
    attn_band<<<dim3(8192), dim3(256), 0, stream>>>(qkv_bf, ctx_bf);
    attn_global<<<dim3(16), dim3(256), 0, stream>>>(qkv_bf, ctx_bf);
    gemm_bt<1><<<dim3(65, 2), dim3(256), 0, stream>>>(ctx_bf, wo_bf, out_proj_b, x,
                                                      (void*)x1, M, 256, 256);
    rmsnorm_kernel<<<dim3((M + 3) / 4), dim3(256), 0, stream>>>(x1, norm2_w, h2_bf, M);
    gemm_bt<2><<<dim3(65, 4), dim3(256), 0, stream>>>(h2_bf, w1_bf, b1, (const float*)nullptr,
                                                      (void*)g_bf, M, 512, 256);
    gemm_bt<1><<<dim3(65, 2), dim3(256), 0, stream>>>(g_bf, w2_bf, b2, x1,
                                                      (void*)out, M, 256, 512);
}

// Round 4
// 259.199 us; speedup vs baseline: 1.9364x; 1.9364x over previous
//
#include <hip/hip_runtime.h>
#include <hip/hip_bf16.h>
#include <math.h>

#define BATCH 4
#define SEQ 2049
#define DIMD 256
#define NHEAD 4
#define DH 64
#define WIN 64
#define M_ROWS (BATCH * SEQ) // 8196

#define QBLK 33              // 33 query-tiles of 64 covering 2049 rows
#define TSLOTS 224           // 14 key-blocks of 16
#define VSTR 232             // padded LDS stride (elems)

typedef __attribute__((ext_vector_type(8))) short short8;
typedef __attribute__((ext_vector_type(4))) float f32x4;
typedef __hip_bfloat16 bf16;

__device__ __forceinline__ float b2f(short u) {
    union { unsigned int i; float f; } c;
    c.i = ((unsigned int)(unsigned short)u) << 16;
    return c.f;
}
__device__ __forceinline__ short f2b(float f) {
    bf16 h = __float2bfloat16(f);
    return *reinterpret_cast<short*>(&h);
}

// ---------------- weight fp32 -> bf16 conversion ----------------
__global__ __launch_bounds__(256) void cvt_weights(
        const float* __restrict__ wq, const float* __restrict__ wo,
        const float* __restrict__ w1, const float* __restrict__ w2,
        bf16* __restrict__ oq, bf16* __restrict__ oo,
        bf16* __restrict__ o1, bf16* __restrict__ o2) {
    int i = blockIdx.x * 256 + threadIdx.x;
    if (i < 196608)      oq[i]          = __float2bfloat16(wq[i]);
    else if (i < 262144) oo[i - 196608] = __float2bfloat16(wo[i - 196608]);
    else if (i < 393216) o1[i - 262144] = __float2bfloat16(w1[i - 262144]);
    else                 o2[i - 393216] = __float2bfloat16(w2[i - 393216]);
}

// ---------------- RMSNorm: fp32 in -> bf16 out (1 wave per row) ----------------
__global__ __launch_bounds__(256) void rmsnorm_kernel(const float* __restrict__ x,
        const float* __restrict__ w, bf16* __restrict__ h, int M) {
    int wid = threadIdx.x >> 6, lane = threadIdx.x & 63;
    int row = blockIdx.x * 4 + wid;
    if (row >= M) return;
    const float4 v = reinterpret_cast<const float4*>(x + (size_t)row * DIMD)[lane];
    float ss = v.x * v.x + v.y * v.y + v.z * v.z + v.w * v.w;
    #pragma unroll
    for (int o = 1; o < 64; o <<= 1) ss += __shfl_xor(ss, o, 64);
    float r = rsqrtf(ss * (1.0f / DIMD) + 1e-6f);
    const float4 wv = reinterpret_cast<const float4*>(w)[lane];
    bf16* hp = h + (size_t)row * DIMD + lane * 4;
    hp[0] = __float2bfloat16(v.x * r * wv.x);
    hp[1] = __float2bfloat16(v.y * r * wv.y);
    hp[2] = __float2bfloat16(v.z * r * wv.z);
    hp[3] = __float2bfloat16(v.w * r * wv.w);
}

// ---------------- GEMM C = A * B^T (+bias, epilogue) ----------------
// 64x64 block tile, 4 waves each 32x32 (2x2 frags).
// MODE 0: bf16(acc+bias). MODE 1: f32(acc+bias+resid). MODE 2: bf16(gelu(acc+bias)).
template<int MODE>
__global__ __launch_bounds__(256) void gemm_bt(
        const bf16* __restrict__ A, const bf16* __restrict__ B,
        const float* __restrict__ bias, const float* __restrict__ resid,
        void* __restrict__ C, int M, int N, int K) {
    int lane = threadIdx.x & 63, wid = threadIdx.x >> 6;
    int m0 = blockIdx.x * 64 + (wid >> 1) * 32;
    int n0 = blockIdx.y * 64 + (wid & 1) * 32;
    int lrow = lane & 15;
    int koff = (lane >> 4) * 8;
    f32x4 acc[2][2];
    #pragma unroll
    for (int i = 0; i < 2; i++)
        #pragma unroll
        for (int j = 0; j < 2; j++) acc[i][j] = (f32x4){0.f, 0.f, 0.f, 0.f};

    for (int k0 = 0; k0 < K; k0 += 32) {
        short8 a[2], b[2];
        #pragma unroll
        for (int mi = 0; mi < 2; mi++) {
            int row = m0 + mi * 16 + lrow;
            if (row > M - 1) row = M - 1;
            a[mi] = *reinterpret_cast<const short8*>(A + (size_t)row * K + k0 + koff);
        }
        #pragma unroll
        for (int ni = 0; ni < 2; ni++) {
            int col = n0 + ni * 16 + lrow;
            b[ni] = *reinterpret_cast<const short8*>(B + (size_t)col * K + k0 + koff);
        }
        #pragma unroll
        for (int mi = 0; mi < 2; mi++)
            #pragma unroll
            for (int ni = 0; ni < 2; ni++)
                acc[mi][ni] = __builtin_amdgcn_mfma_f32_16x16x32_bf16(a[mi], b[ni], acc[mi][ni], 0, 0, 0);
    }

    int c0 = lane & 15, r0 = (lane >> 4) * 4;
    #pragma unroll
    for (int mi = 0; mi < 2; mi++) {
        #pragma unroll
        for (int ni = 0; ni < 2; ni++) {
            int col = n0 + ni * 16 + c0;
            float bv = bias[col];
            #pragma unroll
            for (int j = 0; j < 4; j++) {
                int row = m0 + mi * 16 + r0 + j;
                if (row < M) {
                    float v = acc[mi][ni][j] + bv;
                    if (MODE == 2) v = 0.5f * v * (1.0f + erff(v * 0.70710678118654752f));
                    if (MODE == 1) {
                        v += resid[(size_t)row * N + col];
                        reinterpret_cast<float*>(C)[(size_t)row * N + col] = v;
                    } else {
                        reinterpret_cast<bf16*>(C)[(size_t)row * N + col] = __float2bfloat16(v);
                    }
                }
            }
        }
    }
}

// ---------------- MFMA banded attention ----------------
// Block = (b,h,qtile64), 4 waves x 16 queries. Key slot t: t<nv -> j=jbase+t,
// t==192 -> j=0 (iff jbase>0), rest invalid (V zeroed, scores masked).
__global__ __launch_bounds__(256) void attn_band_mfma(const short* __restrict__ qkv,
                                                      short* __restrict__ ctx) {
    __shared__ short vt[64][VSTR];            // V^T: [d][slot]
    __shared__ short p_lds[4][16][VSTR];      // per-wave P: [q][slot]
    const int tid = threadIdx.x, lane = tid & 63, wid = tid >> 6;
    const int qb = blockIdx.x % QBLK;
    const int bh = blockIdx.x / QBLK;
    const int b = bh >> 2, h = bh & 3;
    const int q0b = qb * 64;
    int jbase = q0b - 64; if (jbase < 0) jbase = 0;
    int jend = q0b + 127; if (jend > SEQ - 1) jend = SEQ - 1;
    const int nv = jend - jbase + 1;
    const size_t rbase = (size_t)b * SEQ;

    // ---- stage V^T (zero-fill invalid slots) ----
    for (int idx = tid; idx < TSLOTS * 16; idx += 256) {
        int t = idx >> 4;
        int dg = (idx & 15) << 2;
        int j = 0; bool val = false;
        if (t < nv) { j = jbase + t; val = true; }
        else if (t == 192 && jbase > 0) { j = 0; val = true; }
        short4 vv = {0, 0, 0, 0};
        if (val) vv = *reinterpret_cast<const short4*>(qkv + (rbase + j) * 768 + 512 + h * 64 + dg);
        vt[dg + 0][t] = vv.x;
        vt[dg + 1][t] = vv.y;
        vt[dg + 2][t] = vv.z;
        vt[dg + 3][t] = vv.w;
    }

    const int lrow = lane & 15;
    const int koff = (lane >> 4) * 8;
    const int c0 = lrow, r0 = (lane >> 4) * 4;
    const int q0w = q0b + wid * 16;

    // ---- Q fragments (2 x K=32) ----
    int qrow = q0w + lrow; if (qrow > SEQ - 1) qrow = SEQ - 1;
    const short* qp = qkv + (rbase + qrow) * 768 + h * 64;
    short8 aq0 = *reinterpret_cast<const short8*>(qp + koff);
    short8 aq1 = *reinterpret_cast<const short8*>(qp + 32 + koff);

    // ---- QK^T over 14 key-blocks ----
    f32x4 s[14];
    #pragma unroll
    for (int n = 0; n < 14; n++) {
        int t = n * 16 + lrow;
        int j = (t < nv) ? (jbase + t) : 0;   // t==192 also maps to j=0
        const short* kp = qkv + (rbase + j) * 768 + 256 + h * 64;
        short8 bk0 = *reinterpret_cast<const short8*>(kp + koff);
        short8 bk1 = *reinterpret_cast<const short8*>(kp + 32 + koff);
        f32x4 acc = (f32x4){0.f, 0.f, 0.f, 0.f};
        acc = __builtin_amdgcn_mfma_f32_16x16x32_bf16(aq0, bk0, acc, 0, 0, 0);
        acc = __builtin_amdgcn_mfma_f32_16x16x32_bf16(aq1, bk1, acc, 0, 0, 0);
        s[n] = acc;
    }

    // ---- mask + scale (log2 domain) ----
    const float SC = 0.125f * 1.44269504088896340736f;
    float m4[4] = {-1e30f, -1e30f, -1e30f, -1e30f};
    #pragma unroll
    for (int n = 0; n < 14; n++) {
        int t = n * 16 + c0;
        bool tval = (t < nv) || (t == 192 && jbase > 0);
        int j = (t < nv) ? (jbase + t) : 0;
        #pragma unroll
        for (int jj = 0; jj < 4; jj++) {
            int q = q0w + r0 + jj;
            int dd = q - j; if (dd < 0) dd = -dd;
            bool allowed = tval && (dd <= WIN || j == 0) && (q < SEQ);
            float v = allowed ? s[n][jj] * SC : -1e30f;
            s[n][jj] = v;
            m4[jj] = fmaxf(m4[jj], v);
        }
    }
    #pragma unroll
    for (int o = 1; o < 16; o <<= 1) {
        #pragma unroll
        for (int jj = 0; jj < 4; jj++) m4[jj] = fmaxf(m4[jj], __shfl_xor(m4[jj], o, 64));
    }

    // ---- exp, row-sum, write P to LDS ----
    float l4[4] = {0.f, 0.f, 0.f, 0.f};
    #pragma unroll
    for (int n = 0; n < 14; n++) {
        #pragma unroll
        for (int jj = 0; jj < 4; jj++) {
            float p = exp2f(s[n][jj] - m4[jj]);
            l4[jj] += p;
            p_lds[wid][r0 + jj][n * 16 + c0] = f2b(p);
        }
    }
    #pragma unroll
    for (int o = 1; o < 16; o <<= 1) {
        #pragma unroll
        for (int jj = 0; jj < 4; jj++) l4[jj] += __shfl_xor(l4[jj], o, 64);
    }

    __syncthreads();

    // ---- PV: O[16 x 64] = P[16 x 224] * V^T ----
    f32x4 o[4];
    #pragma unroll
    for (int dn = 0; dn < 4; dn++) o[dn] = (f32x4){0.f, 0.f, 0.f, 0.f};
    #pragma unroll
    for (int ks = 0; ks < 7; ks++) {
        short8 ap = *reinterpret_cast<const short8*>(&p_lds[wid][lrow][ks * 32 + koff]);
        #pragma unroll
        for (int dn = 0; dn < 4; dn++) {
            short8 bv = *reinterpret_cast<const short8*>(&vt[dn * 16 + lrow][ks * 32 + koff]);
            o[dn] = __builtin_amdgcn_mfma_f32_16x16x32_bf16(ap, bv, o[dn], 0, 0, 0);
        }
    }

    // ---- epilogue: divide by row sum, store ----
    #pragma unroll
    for (int jj = 0; jj < 4; jj++) {
        int q = q0w + r0 + jj;
        if (q < SEQ) {
            float rl = 1.0f / l4[jj];
            #pragma unroll
            for (int dn = 0; dn < 4; dn++)
                ctx[(rbase + q) * 256 + h * 64 + dn * 16 + c0] = f2b(o[dn][jj] * rl);
        }
    }
}

// ---------------- global row q==0 (full attention), 1 block per (b,h) ----------------
__global__ __launch_bounds__(256) void attn_global(const bf16* __restrict__ qkv, bf16* __restrict__ ctx) {
    __shared__ float q_s[64];
    __shared__ float p_s[SEQ];
    __shared__ float redm[4], reds[4], osum[4][64];
    int tid = threadIdx.x, lane = tid & 63, wid = tid >> 6;
    int b = blockIdx.x >> 2, h = blockIdx.x & 3;
    const size_t base = (size_t)b * SEQ;
    if (tid < 64) q_s[tid] = __bfloat162float(qkv[base * 768 + h * 64 + tid]);
    __syncthreads();
    float mx = -1e30f;
    for (int j = tid; j < SEQ; j += 256) {
        const short8* kp = reinterpret_cast<const short8*>(qkv + (base + j) * 768 + 256 + h * 64);
        float s = 0.f;
        #pragma unroll
        for (int d8 = 0; d8 < 8; ++d8) {
            short8 kv = kp[d8];
            #pragma unroll
            for (int e = 0; e < 8; ++e) s += q_s[d8 * 8 + e] * b2f(kv[e]);
        }
        s *= 0.125f;
        p_s[j] = s;
        mx = fmaxf(mx, s);
    }
    #pragma unroll
    for (int o = 1; o < 64; o <<= 1) mx = fmaxf(mx, __shfl_xor(mx, o, 64));
    if (lane == 0) redm[wid] = mx;
    __syncthreads();
    mx = fmaxf(fmaxf(redm[0], redm[1]), fmaxf(redm[2], redm[3]));
    float sum = 0.f;
    for (int j = tid; j < SEQ; j += 256) {
        float p = expf(p_s[j] - mx);
        p_s[j] = p;
        sum += p;
    }
    #pragma unroll
    for (int o = 1; o < 64; o <<= 1) sum += __shfl_xor(sum, o, 64);
    if (lane == 0) reds[wid] = sum;
    __syncthreads();
    sum = reds[0] + reds[1] + reds[2] + reds[3];
    float oa0 = 0.f, oa1 = 0.f, oa2 = 0.f, oa3 = 0.f;
    for (int j = wid; j < SEQ; j += 16) {
        oa0 += p_s[j] * __bfloat162float(qkv[(base + j) * 768 + 512 + h * 64 + lane]);
        if (j + 4 < SEQ)  oa1 += p_s[j + 4]  * __bfloat162float(qkv[(base + j + 4)  * 768 + 512 + h * 64 + lane]);
        if (j + 8 < SEQ)  oa2 += p_s[j + 8]  * __bfloat162float(qkv[(base + j + 8)  * 768 + 512 + h * 64 + lane]);
        if (j + 12 < SEQ) oa3 += p_s[j + 12] * __bfloat162float(qkv[(base + j + 12) * 768 + 512 + h * 64 + lane]);
    }
    float o_acc = (oa0 + oa1) + (oa2 + oa3);
    osum[wid][lane] = o_acc;
    __syncthreads();
    if (wid == 0) {
        float o = osum[0][lane] + osum[1][lane] + osum[2][lane] + osum[3][lane];
        ctx[base * 256 + h * 64 + lane] = __float2bfloat16(o / sum);
    }
}

extern "C" void kernel_launch(void* const* d_in, const int* in_sizes, int n_in,
                              void* d_out, int out_size, void* d_ws, size_t ws_size,
                              hipStream_t stream) {
    const float* x         = (const float*)d_in[0];
    const float* norm1_w   = (const float*)d_in[1];
    const float* in_proj_w = (const float*)d_in[2];
    const float* in_proj_b = (const float*)d_in[3];
    const float* out_proj_w= (const float*)d_in[4];
    const float* out_proj_b= (const float*)d_in[5];
    const float* norm2_w   = (const float*)d_in[6];
    const float* w1        = (const float*)d_in[7];
    const float* b1        = (const float*)d_in[8];
    const float* w2        = (const float*)d_in[9];
    const float* b2        = (const float*)d_in[10];
    float* out = (float*)d_out;

    const int M = M_ROWS; // 8196
    char* ws = (char*)d_ws;
    size_t off = 0;
    auto take = [&](size_t bytes) {
        char* p = ws + off;
        off = (off + bytes + 255) & ~(size_t)255;
        return p;
    };
    bf16* h_bf   = (bf16*)take((size_t)M * 256 * 2);
    bf16* qkv_bf = (bf16*)take((size_t)M * 768 * 2);
    bf16* ctx_bf = (bf16*)take((size_t)M * 256 * 2);
    float* x1    = (float*)take((size_t)M * 256 * 4);
    bf16* h2_bf  = (bf16*)take((size_t)M * 256 * 2);
    bf16* g_bf   = (bf16*)take((size_t)M * 512 * 2);
    bf16* wq_bf  = (bf16*)take(768 * 256 * 2);
    bf16* wo_bf  = (bf16*)take(256 * 256 * 2);
    bf16* w1_bf  = (bf16*)take(512 * 256 * 2);
    bf16* w2_bf  = (bf16*)take(256 * 512 * 2);
    (void)ws_size; (void)in_sizes; (void)n_in; (void)out_size;

    cvt_weights<<<dim3(2048), dim3(256), 0, stream>>>(in_proj_w, out_proj_w, w1, w2,
                                                      wq_bf, wo_bf, w1_bf, w2_bf);
    rmsnorm_kernel<<<dim3((M + 3) / 4), dim3(256), 0, stream>>>(x, norm1_w, h_bf, M);
    gemm_bt<0><<<dim3(129, 12), dim3(256), 0, stream>>>(h_bf, wq_bf, in_proj_b, (const float*)nullptr,
                                                        (void*)qkv_bf, M, 768, 256);
    attn_band_mfma<<<dim3(16 * QBLK), dim3(256), 0, stream>>>((const short*)qkv_bf, (short*)ctx_bf);
    attn_global<<<dim3(16), dim3(256), 0, stream>>>(qkv_bf, ctx_bf);
    gemm_bt<1><<<dim3(129, 4), dim3(256), 0, stream>>>(ctx_bf, wo_bf, out_proj_b, x,
                                                       (void*)x1, M, 256, 256);
    rmsnorm_kernel<<<dim3((M + 3) / 4), dim3(256), 0, stream>>>(x1, norm2_w, h2_bf, M);
    gemm_bt<2><<<dim3(129, 8), dim3(256), 0, stream>>>(h2_bf, w1_bf, b1, (const float*)nullptr,
                                                       (void*)g_bf, M, 512, 256);
    gemm_bt<1><<<dim3(129, 4), dim3(256), 0, stream>>>(g_bf, w2_bf, b2, x1,
                                                       (void*)out, M, 256, 512);
}

// Round 5
// 165.884 us; speedup vs baseline: 3.0258x; 1.5625x over previous
//
#include <hip/hip_runtime.h>
#include <hip/hip_bf16.h>
#include <math.h>

#define BATCH 4
#define SEQ 2049
#define DIMD 256
#define NHEAD 4
#define DH 64
#define WIN 64
#define M_ROWS (BATCH * SEQ) // 8196

#define QBLK 33              // 33 query-tiles of 64 covering 2049 rows
#define TSLOTS 224           // 14 key-blocks of 16
#define VSTR 232             // padded LDS stride (elems)

#define NSPLIT 9             // key splits for the q==0 global rows
#define SPLITK 228           // ceil(2049/9)

typedef __attribute__((ext_vector_type(8))) short short8;
typedef __attribute__((ext_vector_type(4))) float f32x4;
typedef __hip_bfloat16 bf16;

__device__ __forceinline__ float b2f(short u) {
    union { unsigned int i; float f; } c;
    c.i = ((unsigned int)(unsigned short)u) << 16;
    return c.f;
}
__device__ __forceinline__ short f2b(float f) {
    bf16 h = __float2bfloat16(f);
    return *reinterpret_cast<short*>(&h);
}

// ---------------- weight fp32 -> bf16 conversion ----------------
__global__ __launch_bounds__(256) void cvt_weights(
        const float* __restrict__ wq, const float* __restrict__ wo,
        const float* __restrict__ w1, const float* __restrict__ w2,
        bf16* __restrict__ oq, bf16* __restrict__ oo,
        bf16* __restrict__ o1, bf16* __restrict__ o2) {
    int i = blockIdx.x * 256 + threadIdx.x;
    if (i < 196608)      oq[i]          = __float2bfloat16(wq[i]);
    else if (i < 262144) oo[i - 196608] = __float2bfloat16(wo[i - 196608]);
    else if (i < 393216) o1[i - 262144] = __float2bfloat16(w1[i - 262144]);
    else                 o2[i - 393216] = __float2bfloat16(w2[i - 393216]);
}

// ---------------- RMSNorm: fp32 in -> bf16 out (1 wave per row) ----------------
__global__ __launch_bounds__(256) void rmsnorm_kernel(const float* __restrict__ x,
        const float* __restrict__ w, bf16* __restrict__ h, int M) {
    int wid = threadIdx.x >> 6, lane = threadIdx.x & 63;
    int row = blockIdx.x * 4 + wid;
    if (row >= M) return;
    const float4 v = reinterpret_cast<const float4*>(x + (size_t)row * DIMD)[lane];
    float ss = v.x * v.x + v.y * v.y + v.z * v.z + v.w * v.w;
    #pragma unroll
    for (int o = 1; o < 64; o <<= 1) ss += __shfl_xor(ss, o, 64);
    float r = rsqrtf(ss * (1.0f / DIMD) + 1e-6f);
    const float4 wv = reinterpret_cast<const float4*>(w)[lane];
    bf16* hp = h + (size_t)row * DIMD + lane * 4;
    hp[0] = __float2bfloat16(v.x * r * wv.x);
    hp[1] = __float2bfloat16(v.y * r * wv.y);
    hp[2] = __float2bfloat16(v.z * r * wv.z);
    hp[3] = __float2bfloat16(v.w * r * wv.w);
}

// ---------------- GEMM C = A * B^T (+bias, epilogue) ----------------
// 64x64 block tile, 4 waves each 32x32 (2x2 frags).
// MODE 0: bf16(acc+bias). MODE 1: f32(acc+bias+resid). MODE 2: bf16(gelu(acc+bias)).
template<int MODE>
__global__ __launch_bounds__(256) void gemm_bt(
        const bf16* __restrict__ A, const bf16* __restrict__ B,
        const float* __restrict__ bias, const float* __restrict__ resid,
        void* __restrict__ C, int M, int N, int K) {
    int lane = threadIdx.x & 63, wid = threadIdx.x >> 6;
    int m0 = blockIdx.x * 64 + (wid >> 1) * 32;
    int n0 = blockIdx.y * 64 + (wid & 1) * 32;
    int lrow = lane & 15;
    int koff = (lane >> 4) * 8;
    f32x4 acc[2][2];
    #pragma unroll
    for (int i = 0; i < 2; i++)
        #pragma unroll
        for (int j = 0; j < 2; j++) acc[i][j] = (f32x4){0.f, 0.f, 0.f, 0.f};

    for (int k0 = 0; k0 < K; k0 += 32) {
        short8 a[2], b[2];
        #pragma unroll
        for (int mi = 0; mi < 2; mi++) {
            int row = m0 + mi * 16 + lrow;
            if (row > M - 1) row = M - 1;
            a[mi] = *reinterpret_cast<const short8*>(A + (size_t)row * K + k0 + koff);
        }
        #pragma unroll
        for (int ni = 0; ni < 2; ni++) {
            int col = n0 + ni * 16 + lrow;
            b[ni] = *reinterpret_cast<const short8*>(B + (size_t)col * K + k0 + koff);
        }
        #pragma unroll
        for (int mi = 0; mi < 2; mi++)
            #pragma unroll
            for (int ni = 0; ni < 2; ni++)
                acc[mi][ni] = __builtin_amdgcn_mfma_f32_16x16x32_bf16(a[mi], b[ni], acc[mi][ni], 0, 0, 0);
    }

    int c0 = lane & 15, r0 = (lane >> 4) * 4;
    #pragma unroll
    for (int mi = 0; mi < 2; mi++) {
        #pragma unroll
        for (int ni = 0; ni < 2; ni++) {
            int col = n0 + ni * 16 + c0;
            float bv = bias[col];
            #pragma unroll
            for (int j = 0; j < 4; j++) {
                int row = m0 + mi * 16 + r0 + j;
                if (row < M) {
                    float v = acc[mi][ni][j] + bv;
                    if (MODE == 2) v = 0.5f * v * (1.0f + erff(v * 0.70710678118654752f));
                    if (MODE == 1) {
                        v += resid[(size_t)row * N + col];
                        reinterpret_cast<float*>(C)[(size_t)row * N + col] = v;
                    } else {
                        reinterpret_cast<bf16*>(C)[(size_t)row * N + col] = __float2bfloat16(v);
                    }
                }
            }
        }
    }
}

// ---------------- MFMA banded attention (queries, incl. q=0 later overwritten) ----------------
__global__ __launch_bounds__(256) void attn_band_mfma(const short* __restrict__ qkv,
                                                      short* __restrict__ ctx) {
    __shared__ short vt[64][VSTR];            // V^T: [d][slot]
    __shared__ short p_lds[4][16][VSTR];      // per-wave P: [q][slot]
    const int tid = threadIdx.x, lane = tid & 63, wid = tid >> 6;
    const int qb = blockIdx.x % QBLK;
    const int bh = blockIdx.x / QBLK;
    const int b = bh >> 2, h = bh & 3;
    const int q0b = qb * 64;
    int jbase = q0b - 64; if (jbase < 0) jbase = 0;
    int jend = q0b + 127; if (jend > SEQ - 1) jend = SEQ - 1;
    const int nv = jend - jbase + 1;
    const size_t rbase = (size_t)b * SEQ;

    // ---- stage V^T (zero-fill invalid slots) ----
    for (int idx = tid; idx < TSLOTS * 16; idx += 256) {
        int t = idx >> 4;
        int dg = (idx & 15) << 2;
        int j = 0; bool val = false;
        if (t < nv) { j = jbase + t; val = true; }
        else if (t == 192 && jbase > 0) { j = 0; val = true; }
        short4 vv = {0, 0, 0, 0};
        if (val) vv = *reinterpret_cast<const short4*>(qkv + (rbase + j) * 768 + 512 + h * 64 + dg);
        vt[dg + 0][t] = vv.x;
        vt[dg + 1][t] = vv.y;
        vt[dg + 2][t] = vv.z;
        vt[dg + 3][t] = vv.w;
    }

    const int lrow = lane & 15;
    const int koff = (lane >> 4) * 8;
    const int c0 = lrow, r0 = (lane >> 4) * 4;
    const int q0w = q0b + wid * 16;

    // ---- Q fragments (2 x K=32) ----
    int qrow = q0w + lrow; if (qrow > SEQ - 1) qrow = SEQ - 1;
    const short* qp = qkv + (rbase + qrow) * 768 + h * 64;
    short8 aq0 = *reinterpret_cast<const short8*>(qp + koff);
    short8 aq1 = *reinterpret_cast<const short8*>(qp + 32 + koff);

    // ---- QK^T over 14 key-blocks ----
    f32x4 s[14];
    #pragma unroll
    for (int n = 0; n < 14; n++) {
        int t = n * 16 + lrow;
        int j = (t < nv) ? (jbase + t) : 0;   // t==192 also maps to j=0
        const short* kp = qkv + (rbase + j) * 768 + 256 + h * 64;
        short8 bk0 = *reinterpret_cast<const short8*>(kp + koff);
        short8 bk1 = *reinterpret_cast<const short8*>(kp + 32 + koff);
        f32x4 acc = (f32x4){0.f, 0.f, 0.f, 0.f};
        acc = __builtin_amdgcn_mfma_f32_16x16x32_bf16(aq0, bk0, acc, 0, 0, 0);
        acc = __builtin_amdgcn_mfma_f32_16x16x32_bf16(aq1, bk1, acc, 0, 0, 0);
        s[n] = acc;
    }

    // ---- mask + scale (log2 domain) ----
    const float SC = 0.125f * 1.44269504088896340736f;
    float m4[4] = {-1e30f, -1e30f, -1e30f, -1e30f};
    #pragma unroll
    for (int n = 0; n < 14; n++) {
        int t = n * 16 + c0;
        bool tval = (t < nv) || (t == 192 && jbase > 0);
        int j = (t < nv) ? (jbase + t) : 0;
        #pragma unroll
        for (int jj = 0; jj < 4; jj++) {
            int q = q0w + r0 + jj;
            int dd = q - j; if (dd < 0) dd = -dd;
            bool allowed = tval && (dd <= WIN || j == 0) && (q < SEQ);
            float v = allowed ? s[n][jj] * SC : -1e30f;
            s[n][jj] = v;
            m4[jj] = fmaxf(m4[jj], v);
        }
    }
    #pragma unroll
    for (int o = 1; o < 16; o <<= 1) {
        #pragma unroll
        for (int jj = 0; jj < 4; jj++) m4[jj] = fmaxf(m4[jj], __shfl_xor(m4[jj], o, 64));
    }

    // ---- exp, row-sum, write P to LDS ----
    float l4[4] = {0.f, 0.f, 0.f, 0.f};
    #pragma unroll
    for (int n = 0; n < 14; n++) {
        #pragma unroll
        for (int jj = 0; jj < 4; jj++) {
            float p = exp2f(s[n][jj] - m4[jj]);
            l4[jj] += p;
            p_lds[wid][r0 + jj][n * 16 + c0] = f2b(p);
        }
    }
    #pragma unroll
    for (int o = 1; o < 16; o <<= 1) {
        #pragma unroll
        for (int jj = 0; jj < 4; jj++) l4[jj] += __shfl_xor(l4[jj], o, 64);
    }

    __syncthreads();

    // ---- PV: O[16 x 64] = P[16 x 224] * V^T ----
    f32x4 o[4];
    #pragma unroll
    for (int dn = 0; dn < 4; dn++) o[dn] = (f32x4){0.f, 0.f, 0.f, 0.f};
    #pragma unroll
    for (int ks = 0; ks < 7; ks++) {
        short8 ap = *reinterpret_cast<const short8*>(&p_lds[wid][lrow][ks * 32 + koff]);
        #pragma unroll
        for (int dn = 0; dn < 4; dn++) {
            short8 bv = *reinterpret_cast<const short8*>(&vt[dn * 16 + lrow][ks * 32 + koff]);
            o[dn] = __builtin_amdgcn_mfma_f32_16x16x32_bf16(ap, bv, o[dn], 0, 0, 0);
        }
    }

    // ---- epilogue: divide by row sum, store ----
    #pragma unroll
    for (int jj = 0; jj < 4; jj++) {
        int q = q0w + r0 + jj;
        if (q < SEQ) {
            float rl = 1.0f / l4[jj];
            #pragma unroll
            for (int dn = 0; dn < 4; dn++)
                ctx[(rbase + q) * 256 + h * 64 + dn * 16 + c0] = f2b(o[dn][jj] * rl);
        }
    }
}

// ---------------- global row q==0: split-K partials ----------------
// grid = 16*(NSPLIT); block 256. Each block: keys [s*SPLITK, min(SEQ,...)).
// Writes per (bh,s): part[66] = { o[64] (f32), m, l }.
__global__ __launch_bounds__(256) void attn_global_partial(const bf16* __restrict__ qkv,
                                                           float* __restrict__ part) {
    __shared__ float q_s[64];
    __shared__ float p_s[SPLITK];
    __shared__ float redm[4], redl[4];
    __shared__ float osum[4][64];
    const int tid = threadIdx.x, lane = tid & 63, wid = tid >> 6;
    const int s = blockIdx.x % NSPLIT;
    const int bh = blockIdx.x / NSPLIT;
    const int b = bh >> 2, h = bh & 3;
    const size_t base = (size_t)b * SEQ;
    const int j0 = s * SPLITK;
    const int j1 = (j0 + SPLITK < SEQ) ? (j0 + SPLITK) : SEQ;
    const int nk = j1 - j0;

    if (tid < 64) q_s[tid] = __bfloat162float(qkv[base * 768 + h * 64 + tid]);
    __syncthreads();

    // score for this thread's key
    float sc = -1e30f;
    if (tid < nk) {
        const short8* kp = reinterpret_cast<const short8*>(
            reinterpret_cast<const short*>(qkv) + (base + j0 + tid) * 768 + 256 + h * 64);
        float acc = 0.f;
        #pragma unroll
        for (int d8 = 0; d8 < 8; ++d8) {
            short8 kv = kp[d8];
            #pragma unroll
            for (int e = 0; e < 8; ++e) acc += q_s[d8 * 8 + e] * b2f(kv[e]);
        }
        sc = acc * 0.125f;
    }
    float mx = sc;
    #pragma unroll
    for (int o = 1; o < 64; o <<= 1) mx = fmaxf(mx, __shfl_xor(mx, o, 64));
    if (lane == 0) redm[wid] = mx;
    __syncthreads();
    mx = fmaxf(fmaxf(redm[0], redm[1]), fmaxf(redm[2], redm[3]));

    float p = (tid < nk) ? expf(sc - mx) : 0.f;
    if (tid < SPLITK) p_s[tid] = p;
    float l = p;
    #pragma unroll
    for (int o = 1; o < 64; o <<= 1) l += __shfl_xor(l, o, 64);
    if (lane == 0) redl[wid] = l;
    __syncthreads();
    l = redl[0] + redl[1] + redl[2] + redl[3];

    // PV partial: two interleaved chains; lane = dim, wid strides keys
    float oa0 = 0.f, oa1 = 0.f;
    for (int i = wid; i < SPLITK; i += 8) {
        float v0 = 0.f, v1 = 0.f;
        if (i < nk)     v0 = __bfloat162float(qkv[(base + j0 + i) * 768 + 512 + h * 64 + lane]);
        if (i + 4 < nk) v1 = __bfloat162float(qkv[(base + j0 + i + 4) * 768 + 512 + h * 64 + lane]);
        oa0 += p_s[i] * v0;
        if (i + 4 < SPLITK) oa1 += p_s[i + 4] * v1;
    }
    osum[wid][lane] = oa0 + oa1;
    __syncthreads();
    if (wid == 0) {
        float o = osum[0][lane] + osum[1][lane] + osum[2][lane] + osum[3][lane];
        float* pp = part + (size_t)(bh * NSPLIT + s) * 66;
        pp[lane] = o;
        if (lane == 0) { pp[64] = mx; pp[65] = l; }
    }
}

// ---------------- global row q==0: combine partials ----------------
__global__ __launch_bounds__(64) void attn_global_combine(const float* __restrict__ part,
                                                          bf16* __restrict__ ctx) {
    const int bh = blockIdx.x;
    const int b = bh >> 2, h = bh & 3;
    const int lane = threadIdx.x;
    float M = -1e30f;
    #pragma unroll
    for (int s = 0; s < NSPLIT; s++) M = fmaxf(M, part[(size_t)(bh * NSPLIT + s) * 66 + 64]);
    float L = 0.f, o = 0.f;
    #pragma unroll
    for (int s = 0; s < NSPLIT; s++) {
        const float* pp = part + (size_t)(bh * NSPLIT + s) * 66;
        float w = expf(pp[64] - M);
        L += pp[65] * w;
        o += pp[lane] * w;
    }
    ctx[(size_t)b * SEQ * 256 + h * 64 + lane] = __float2bfloat16(o / L);
}

extern "C" void kernel_launch(void* const* d_in, const int* in_sizes, int n_in,
                              void* d_out, int out_size, void* d_ws, size_t ws_size,
                              hipStream_t stream) {
    const float* x         = (const float*)d_in[0];
    const float* norm1_w   = (const float*)d_in[1];
    const float* in_proj_w = (const float*)d_in[2];
    const float* in_proj_b = (const float*)d_in[3];
    const float* out_proj_w= (const float*)d_in[4];
    const float* out_proj_b= (const float*)d_in[5];
    const float* norm2_w   = (const float*)d_in[6];
    const float* w1        = (const float*)d_in[7];
    const float* b1        = (const float*)d_in[8];
    const float* w2        = (const float*)d_in[9];
    const float* b2        = (const float*)d_in[10];
    float* out = (float*)d_out;

    const int M = M_ROWS; // 8196
    char* ws = (char*)d_ws;
    size_t off = 0;
    auto take = [&](size_t bytes) {
        char* p = ws + off;
        off = (off + bytes + 255) & ~(size_t)255;
        return p;
    };
    bf16* h_bf   = (bf16*)take((size_t)M * 256 * 2);
    bf16* qkv_bf = (bf16*)take((size_t)M * 768 * 2);
    bf16* ctx_bf = (bf16*)take((size_t)M * 256 * 2);
    float* x1    = (float*)take((size_t)M * 256 * 4);
    bf16* h2_bf  = (bf16*)take((size_t)M * 256 * 2);
    bf16* g_bf   = (bf16*)take((size_t)M * 512 * 2);
    bf16* wq_bf  = (bf16*)take(768 * 256 * 2);
    bf16* wo_bf  = (bf16*)take(256 * 256 * 2);
    bf16* w1_bf  = (bf16*)take(512 * 256 * 2);
    bf16* w2_bf  = (bf16*)take(256 * 512 * 2);
    float* part  = (float*)take((size_t)16 * NSPLIT * 66 * 4);
    (void)ws_size; (void)in_sizes; (void)n_in; (void)out_size;

    cvt_weights<<<dim3(2048), dim3(256), 0, stream>>>(in_proj_w, out_proj_w, w1, w2,
                                                      wq_bf, wo_bf, w1_bf, w2_bf);
    rmsnorm_kernel<<<dim3((M + 3) / 4), dim3(256), 0, stream>>>(x, norm1_w, h_bf, M);
    gemm_bt<0><<<dim3(129, 12), dim3(256), 0, stream>>>(h_bf, wq_bf, in_proj_b, (const float*)nullptr,
                                                        (void*)qkv_bf, M, 768, 256);
    attn_band_mfma<<<dim3(16 * QBLK), dim3(256), 0, stream>>>((const short*)qkv_bf, (short*)ctx_bf);
    attn_global_partial<<<dim3(16 * NSPLIT), dim3(256), 0, stream>>>(qkv_bf, part);
    attn_global_combine<<<dim3(16), dim3(64), 0, stream>>>(part, ctx_bf);
    gemm_bt<1><<<dim3(129, 4), dim3(256), 0, stream>>>(ctx_bf, wo_bf, out_proj_b, x,
                                                       (void*)x1, M, 256, 256);
    rmsnorm_kernel<<<dim3((M + 3) / 4), dim3(256), 0, stream>>>(x1, norm2_w, h2_bf, M);
    gemm_bt<2><<<dim3(129, 8), dim3(256), 0, stream>>>(h2_bf, w1_bf, b1, (const float*)nullptr,
                                                       (void*)g_bf, M, 512, 256);
    gemm_bt<1><<<dim3(129, 4), dim3(256), 0, stream>>>(g_bf, w2_bf, b2, x1,
                                                       (void*)out, M, 256, 512);
}

// Round 6
// 148.695 us; speedup vs baseline: 3.3755x; 1.1156x over previous
//
#include <hip/hip_runtime.h>
#include <hip/hip_bf16.h>
#include <math.h>

#define BATCH 4
#define SEQ 2049
#define DIMD 256
#define NHEAD 4
#define DH 64
#define WIN 64
#define M_ROWS (BATCH * SEQ) // 8196
#define M_PAD 8320           // 65 * 128, padded rows for unguarded A-tile loads

#define QBLK 33              // 33 query-tiles of 64 covering 2049 rows
#define TSLOTS 224           // 14 key-blocks of 16
#define VSTR 232             // padded LDS stride (elems)

#define NSPLIT 9             // key splits for the q==0 global rows
#define SPLITK 228           // ceil(2049/9)

typedef __attribute__((ext_vector_type(8))) short short8;
typedef __attribute__((ext_vector_type(4))) float f32x4;
typedef __hip_bfloat16 bf16;

__device__ __forceinline__ float b2f(short u) {
    union { unsigned int i; float f; } c;
    c.i = ((unsigned int)(unsigned short)u) << 16;
    return c.f;
}
__device__ __forceinline__ short f2b(float f) {
    bf16 h = __float2bfloat16(f);
    return *reinterpret_cast<short*>(&h);
}

// ---------------- weight fp32 -> bf16 conversion ----------------
__global__ __launch_bounds__(256) void cvt_weights(
        const float* __restrict__ wq, const float* __restrict__ wo,
        const float* __restrict__ w1, const float* __restrict__ w2,
        bf16* __restrict__ oq, bf16* __restrict__ oo,
        bf16* __restrict__ o1, bf16* __restrict__ o2) {
    int i = blockIdx.x * 256 + threadIdx.x;
    if (i < 196608)      oq[i]          = __float2bfloat16(wq[i]);
    else if (i < 262144) oo[i - 196608] = __float2bfloat16(wo[i - 196608]);
    else if (i < 393216) o1[i - 262144] = __float2bfloat16(w1[i - 262144]);
    else                 o2[i - 393216] = __float2bfloat16(w2[i - 393216]);
}

// ---------------- RMSNorm: fp32 in -> bf16 out (1 wave per row) ----------------
__global__ __launch_bounds__(256) void rmsnorm_kernel(const float* __restrict__ x,
        const float* __restrict__ w, bf16* __restrict__ h, int M) {
    int wid = threadIdx.x >> 6, lane = threadIdx.x & 63;
    int row = blockIdx.x * 4 + wid;
    if (row >= M) return;
    const float4 v = reinterpret_cast<const float4*>(x + (size_t)row * DIMD)[lane];
    float ss = v.x * v.x + v.y * v.y + v.z * v.z + v.w * v.w;
    #pragma unroll
    for (int o = 1; o < 64; o <<= 1) ss += __shfl_xor(ss, o, 64);
    float r = rsqrtf(ss * (1.0f / DIMD) + 1e-6f);
    const float4 wv = reinterpret_cast<const float4*>(w)[lane];
    bf16* hp = h + (size_t)row * DIMD + lane * 4;
    hp[0] = __float2bfloat16(v.x * r * wv.x);
    hp[1] = __float2bfloat16(v.y * r * wv.y);
    hp[2] = __float2bfloat16(v.z * r * wv.z);
    hp[3] = __float2bfloat16(v.w * r * wv.w);
}

// ---------------- LDS-staged GEMM C = A * B^T (+bias, epilogue) ----------------
// BM=128 x BN (128 or 64), BK=32, 4 waves (2x2), wave tile 64 x BN/2.
// LDS layout [kc][row][8] (kc-major, 16B cells): global_load_lds dest is
// linear-in-lane, and quarter-wave ds_read_b128 hits 16 consecutive cells
// (conflict-free by construction).
// MODE 0: bf16(acc+bias). MODE 1: f32(acc+bias+resid). MODE 2: bf16(gelu(acc+bias)).
// A rows must be readable up to blockIdx-padded range (M_PAD); stores guarded by M.
template<int MODE, int BN>
__global__ __launch_bounds__(256) void gemm_lds(
        const bf16* __restrict__ A, const bf16* __restrict__ B,
        const float* __restrict__ bias, const float* __restrict__ resid,
        void* __restrict__ C, int M, int N, int K) {
    constexpr int FN = BN / 32;                 // frags per wave in N
    __shared__ __align__(16) short lA[4 * 128 * 8];
    __shared__ __align__(16) short lB[4 * BN * 8];
    const int tid = threadIdx.x, lane = tid & 63, wid = tid >> 6;
    const int m0 = blockIdx.x * 128;
    const int n0 = blockIdx.y * BN;
    const int wr = wid >> 1, wc = wid & 1;
    const int r = lane & 15, g = lane >> 4;

    f32x4 acc[4][FN];
    #pragma unroll
    for (int i = 0; i < 4; i++)
        #pragma unroll
        for (int j = 0; j < FN; j++) acc[i][j] = (f32x4){0.f, 0.f, 0.f, 0.f};

    for (int k0 = 0; k0 < K; k0 += 32) {
        #pragma unroll
        for (int it = 0; it < 2; ++it) {        // A: 512 cells
            int c = it * 256 + tid;
            int kc = c >> 7, row = c & 127;
            __builtin_amdgcn_global_load_lds(
                (const __attribute__((address_space(1))) void*)(A + (size_t)(m0 + row) * K + k0 + kc * 8),
                (__attribute__((address_space(3))) void*)&lA[c * 8], 16, 0, 0);
        }
        #pragma unroll
        for (int it = 0; it < BN / 64; ++it) {  // B: 4*BN cells
            int c = it * 256 + tid;
            int kc = c / BN, row = c % BN;
            __builtin_amdgcn_global_load_lds(
                (const __attribute__((address_space(1))) void*)(B + (size_t)(n0 + row) * K + k0 + kc * 8),
                (__attribute__((address_space(3))) void*)&lB[c * 8], 16, 0, 0);
        }
        __syncthreads();

        short8 a[4], b[FN];
        #pragma unroll
        for (int mi = 0; mi < 4; mi++)
            a[mi] = *reinterpret_cast<const short8*>(&lA[(g * 128 + wr * 64 + mi * 16 + r) * 8]);
        #pragma unroll
        for (int ni = 0; ni < FN; ni++)
            b[ni] = *reinterpret_cast<const short8*>(&lB[(g * BN + wc * (BN / 2) + ni * 16 + r) * 8]);
        #pragma unroll
        for (int mi = 0; mi < 4; mi++)
            #pragma unroll
            for (int ni = 0; ni < FN; ni++)
                acc[mi][ni] = __builtin_amdgcn_mfma_f32_16x16x32_bf16(a[mi], b[ni], acc[mi][ni], 0, 0, 0);
        __syncthreads();
    }

    const int c0 = lane & 15, r0 = (lane >> 4) * 4;
    #pragma unroll
    for (int mi = 0; mi < 4; mi++) {
        #pragma unroll
        for (int ni = 0; ni < FN; ni++) {
            int col = n0 + wc * (BN / 2) + ni * 16 + c0;
            float bv = bias[col];
            #pragma unroll
            for (int j = 0; j < 4; j++) {
                int row = m0 + wr * 64 + mi * 16 + r0 + j;
                if (row < M) {
                    float v = acc[mi][ni][j] + bv;
                    if (MODE == 2) v = 0.5f * v * (1.0f + erff(v * 0.70710678118654752f));
                    if (MODE == 1) {
                        v += resid[(size_t)row * N + col];
                        reinterpret_cast<float*>(C)[(size_t)row * N + col] = v;
                    } else {
                        reinterpret_cast<bf16*>(C)[(size_t)row * N + col] = __float2bfloat16(v);
                    }
                }
            }
        }
    }
}

// ---------------- MFMA banded attention ----------------
__global__ __launch_bounds__(256) void attn_band_mfma(const short* __restrict__ qkv,
                                                      short* __restrict__ ctx) {
    __shared__ short vt[64][VSTR];            // V^T: [d][slot]
    __shared__ short p_lds[4][16][VSTR];      // per-wave P: [q][slot]
    const int tid = threadIdx.x, lane = tid & 63, wid = tid >> 6;
    const int qb = blockIdx.x % QBLK;
    const int bh = blockIdx.x / QBLK;
    const int b = bh >> 2, h = bh & 3;
    const int q0b = qb * 64;
    int jbase = q0b - 64; if (jbase < 0) jbase = 0;
    int jend = q0b + 127; if (jend > SEQ - 1) jend = SEQ - 1;
    const int nv = jend - jbase + 1;
    const size_t rbase = (size_t)b * SEQ;

    for (int idx = tid; idx < TSLOTS * 16; idx += 256) {
        int t = idx >> 4;
        int dg = (idx & 15) << 2;
        int j = 0; bool val = false;
        if (t < nv) { j = jbase + t; val = true; }
        else if (t == 192 && jbase > 0) { j = 0; val = true; }
        short4 vv = {0, 0, 0, 0};
        if (val) vv = *reinterpret_cast<const short4*>(qkv + (rbase + j) * 768 + 512 + h * 64 + dg);
        vt[dg + 0][t] = vv.x;
        vt[dg + 1][t] = vv.y;
        vt[dg + 2][t] = vv.z;
        vt[dg + 3][t] = vv.w;
    }

    const int lrow = lane & 15;
    const int koff = (lane >> 4) * 8;
    const int c0 = lrow, r0 = (lane >> 4) * 4;
    const int q0w = q0b + wid * 16;

    int qrow = q0w + lrow; if (qrow > SEQ - 1) qrow = SEQ - 1;
    const short* qp = qkv + (rbase + qrow) * 768 + h * 64;
    short8 aq0 = *reinterpret_cast<const short8*>(qp + koff);
    short8 aq1 = *reinterpret_cast<const short8*>(qp + 32 + koff);

    f32x4 s[14];
    #pragma unroll
    for (int n = 0; n < 14; n++) {
        int t = n * 16 + lrow;
        int j = (t < nv) ? (jbase + t) : 0;   // t==192 also maps to j=0
        const short* kp = qkv + (rbase + j) * 768 + 256 + h * 64;
        short8 bk0 = *reinterpret_cast<const short8*>(kp + koff);
        short8 bk1 = *reinterpret_cast<const short8*>(kp + 32 + koff);
        f32x4 acc = (f32x4){0.f, 0.f, 0.f, 0.f};
        acc = __builtin_amdgcn_mfma_f32_16x16x32_bf16(aq0, bk0, acc, 0, 0, 0);
        acc = __builtin_amdgcn_mfma_f32_16x16x32_bf16(aq1, bk1, acc, 0, 0, 0);
        s[n] = acc;
    }

    const float SC = 0.125f * 1.44269504088896340736f;
    float m4[4] = {-1e30f, -1e30f, -1e30f, -1e30f};
    #pragma unroll
    for (int n = 0; n < 14; n++) {
        int t = n * 16 + c0;
        bool tval = (t < nv) || (t == 192 && jbase > 0);
        int j = (t < nv) ? (jbase + t) : 0;
        #pragma unroll
        for (int jj = 0; jj < 4; jj++) {
            int q = q0w + r0 + jj;
            int dd = q - j; if (dd < 0) dd = -dd;
            bool allowed = tval && (dd <= WIN || j == 0) && (q < SEQ);
            float v = allowed ? s[n][jj] * SC : -1e30f;
            s[n][jj] = v;
            m4[jj] = fmaxf(m4[jj], v);
        }
    }
    #pragma unroll
    for (int o = 1; o < 16; o <<= 1) {
        #pragma unroll
        for (int jj = 0; jj < 4; jj++) m4[jj] = fmaxf(m4[jj], __shfl_xor(m4[jj], o, 64));
    }

    float l4[4] = {0.f, 0.f, 0.f, 0.f};
    #pragma unroll
    for (int n = 0; n < 14; n++) {
        #pragma unroll
        for (int jj = 0; jj < 4; jj++) {
            float p = exp2f(s[n][jj] - m4[jj]);
            l4[jj] += p;
            p_lds[wid][r0 + jj][n * 16 + c0] = f2b(p);
        }
    }
    #pragma unroll
    for (int o = 1; o < 16; o <<= 1) {
        #pragma unroll
        for (int jj = 0; jj < 4; jj++) l4[jj] += __shfl_xor(l4[jj], o, 64);
    }

    __syncthreads();

    f32x4 o[4];
    #pragma unroll
    for (int dn = 0; dn < 4; dn++) o[dn] = (f32x4){0.f, 0.f, 0.f, 0.f};
    #pragma unroll
    for (int ks = 0; ks < 7; ks++) {
        short8 ap = *reinterpret_cast<const short8*>(&p_lds[wid][lrow][ks * 32 + koff]);
        #pragma unroll
        for (int dn = 0; dn < 4; dn++) {
            short8 bv = *reinterpret_cast<const short8*>(&vt[dn * 16 + lrow][ks * 32 + koff]);
            o[dn] = __builtin_amdgcn_mfma_f32_16x16x32_bf16(ap, bv, o[dn], 0, 0, 0);
        }
    }

    #pragma unroll
    for (int jj = 0; jj < 4; jj++) {
        int q = q0w + r0 + jj;
        if (q < SEQ) {
            float rl = 1.0f / l4[jj];
            #pragma unroll
            for (int dn = 0; dn < 4; dn++)
                ctx[(rbase + q) * 256 + h * 64 + dn * 16 + c0] = f2b(o[dn][jj] * rl);
        }
    }
}

// ---------------- global row q==0: split-K partials ----------------
__global__ __launch_bounds__(256) void attn_global_partial(const bf16* __restrict__ qkv,
                                                           float* __restrict__ part) {
    __shared__ float q_s[64];
    __shared__ float p_s[SPLITK];
    __shared__ float redm[4], redl[4];
    __shared__ float osum[4][64];
    const int tid = threadIdx.x, lane = tid & 63, wid = tid >> 6;
    const int s = blockIdx.x % NSPLIT;
    const int bh = blockIdx.x / NSPLIT;
    const int b = bh >> 2, h = bh & 3;
    const size_t base = (size_t)b * SEQ;
    const int j0 = s * SPLITK;
    const int j1 = (j0 + SPLITK < SEQ) ? (j0 + SPLITK) : SEQ;
    const int nk = j1 - j0;

    if (tid < 64) q_s[tid] = __bfloat162float(qkv[base * 768 + h * 64 + tid]);
    __syncthreads();

    float sc = -1e30f;
    if (tid < nk) {
        const short8* kp = reinterpret_cast<const short8*>(
            reinterpret_cast<const short*>(qkv) + (base + j0 + tid) * 768 + 256 + h * 64);
        float acc = 0.f;
        #pragma unroll
        for (int d8 = 0; d8 < 8; ++d8) {
            short8 kv = kp[d8];
            #pragma unroll
            for (int e = 0; e < 8; ++e) acc += q_s[d8 * 8 + e] * b2f(kv[e]);
        }
        sc = acc * 0.125f;
    }
    float mx = sc;
    #pragma unroll
    for (int o = 1; o < 64; o <<= 1) mx = fmaxf(mx, __shfl_xor(mx, o, 64));
    if (lane == 0) redm[wid] = mx;
    __syncthreads();
    mx = fmaxf(fmaxf(redm[0], redm[1]), fmaxf(redm[2], redm[3]));

    float p = (tid < nk) ? expf(sc - mx) : 0.f;
    if (tid < SPLITK) p_s[tid] = p;
    float l = p;
    #pragma unroll
    for (int o = 1; o < 64; o <<= 1) l += __shfl_xor(l, o, 64);
    if (lane == 0) redl[wid] = l;
    __syncthreads();
    l = redl[0] + redl[1] + redl[2] + redl[3];

    float oa0 = 0.f, oa1 = 0.f;
    for (int i = wid; i < SPLITK; i += 8) {
        float v0 = 0.f, v1 = 0.f;
        if (i < nk)     v0 = __bfloat162float(qkv[(base + j0 + i) * 768 + 512 + h * 64 + lane]);
        if (i + 4 < nk) v1 = __bfloat162float(qkv[(base + j0 + i + 4) * 768 + 512 + h * 64 + lane]);
        oa0 += p_s[i] * v0;
        if (i + 4 < SPLITK) oa1 += p_s[i + 4] * v1;
    }
    osum[wid][lane] = oa0 + oa1;
    __syncthreads();
    if (wid == 0) {
        float o = osum[0][lane] + osum[1][lane] + osum[2][lane] + osum[3][lane];
        float* pp = part + (size_t)(bh * NSPLIT + s) * 66;
        pp[lane] = o;
        if (lane == 0) { pp[64] = mx; pp[65] = l; }
    }
}

// ---------------- global row q==0: combine partials ----------------
__global__ __launch_bounds__(64) void attn_global_combine(const float* __restrict__ part,
                                                          bf16* __restrict__ ctx) {
    const int bh = blockIdx.x;
    const int b = bh >> 2, h = bh & 3;
    const int lane = threadIdx.x;
    float M = -1e30f;
    #pragma unroll
    for (int s = 0; s < NSPLIT; s++) M = fmaxf(M, part[(size_t)(bh * NSPLIT + s) * 66 + 64]);
    float L = 0.f, o = 0.f;
    #pragma unroll
    for (int s = 0; s < NSPLIT; s++) {
        const float* pp = part + (size_t)(bh * NSPLIT + s) * 66;
        float w = expf(pp[64] - M);
        L += pp[65] * w;
        o += pp[lane] * w;
    }
    ctx[(size_t)b * SEQ * 256 + h * 64 + lane] = __float2bfloat16(o / L);
}

extern "C" void kernel_launch(void* const* d_in, const int* in_sizes, int n_in,
                              void* d_out, int out_size, void* d_ws, size_t ws_size,
                              hipStream_t stream) {
    const float* x         = (const float*)d_in[0];
    const float* norm1_w   = (const float*)d_in[1];
    const float* in_proj_w = (const float*)d_in[2];
    const float* in_proj_b = (const float*)d_in[3];
    const float* out_proj_w= (const float*)d_in[4];
    const float* out_proj_b= (const float*)d_in[5];
    const float* norm2_w   = (const float*)d_in[6];
    const float* w1        = (const float*)d_in[7];
    const float* b1        = (const float*)d_in[8];
    const float* w2        = (const float*)d_in[9];
    const float* b2        = (const float*)d_in[10];
    float* out = (float*)d_out;

    const int M = M_ROWS; // 8196
    char* ws = (char*)d_ws;
    size_t off = 0;
    auto take = [&](size_t bytes) {
        char* p = ws + off;
        off = (off + bytes + 255) & ~(size_t)255;
        return p;
    };
    bf16* h_bf   = (bf16*)take((size_t)M_PAD * 256 * 2);
    bf16* qkv_bf = (bf16*)take((size_t)M_PAD * 768 * 2);
    bf16* ctx_bf = (bf16*)take((size_t)M_PAD * 256 * 2);
    float* x1    = (float*)take((size_t)M_PAD * 256 * 4);
    bf16* h2_bf  = (bf16*)take((size_t)M_PAD * 256 * 2);
    bf16* g_bf   = (bf16*)take((size_t)M_PAD * 512 * 2);
    bf16* wq_bf  = (bf16*)take(768 * 256 * 2);
    bf16* wo_bf  = (bf16*)take(256 * 256 * 2);
    bf16* w1_bf  = (bf16*)take(512 * 256 * 2);
    bf16* w2_bf  = (bf16*)take(256 * 512 * 2);
    float* part  = (float*)take((size_t)16 * NSPLIT * 66 * 4);
    (void)ws_size; (void)in_sizes; (void)n_in; (void)out_size;

    cvt_weights<<<dim3(2048), dim3(256), 0, stream>>>(in_proj_w, out_proj_w, w1, w2,
                                                      wq_bf, wo_bf, w1_bf, w2_bf);
    rmsnorm_kernel<<<dim3((M + 3) / 4), dim3(256), 0, stream>>>(x, norm1_w, h_bf, M);
    gemm_lds<0, 128><<<dim3(65, 6), dim3(256), 0, stream>>>(h_bf, wq_bf, in_proj_b, (const float*)nullptr,
                                                            (void*)qkv_bf, M, 768, 256);
    attn_band_mfma<<<dim3(16 * QBLK), dim3(256), 0, stream>>>((const short*)qkv_bf, (short*)ctx_bf);
    attn_global_partial<<<dim3(16 * NSPLIT), dim3(256), 0, stream>>>(qkv_bf, part);
    attn_global_combine<<<dim3(16), dim3(64), 0, stream>>>(part, ctx_bf);
    gemm_lds<1, 64><<<dim3(65, 4), dim3(256), 0, stream>>>(ctx_bf, wo_bf, out_proj_b, x,
                                                           (void*)x1, M, 256, 256);
    rmsnorm_kernel<<<dim3((M + 3) / 4), dim3(256), 0, stream>>>(x1, norm2_w, h2_bf, M);
    gemm_lds<2, 128><<<dim3(65, 4), dim3(256), 0, stream>>>(h2_bf, w1_bf, b1, (const float*)nullptr,
                                                            (void*)g_bf, M, 512, 256);
    gemm_lds<1, 64><<<dim3(65, 4), dim3(256), 0, stream>>>(g_bf, w2_bf, b2, x1,
                                                           (void*)out, M, 256, 512);
}

// Round 7
// 144.449 us; speedup vs baseline: 3.4748x; 1.0294x over previous
//
#include <hip/hip_runtime.h>
#include <hip/hip_bf16.h>
#include <math.h>

#define BATCH 4
#define SEQ 2049
#define DIMD 256
#define NHEAD 4
#define DH 64
#define WIN 64
#define M_ROWS (BATCH * SEQ) // 8196
#define M_PAD 8320           // 65 * 128, padded rows for unguarded A-tile loads

#define QBLK 33              // 33 query-tiles of 64 covering 2049 rows
#define NKB 10               // per-wave key-blocks of 16 (160 slots)
#define PSTR 168             // p_lds row stride (elems, 16B-aligned)
#define VGUARD 64            // vT zero-guard columns on each side
#define VW 2256              // vT row width: 64 + 2049 + tail guard, mult of 16

#define NSPLIT 9             // key splits for the q==0 global rows
#define SPLITK 228           // ceil(2049/9)

typedef __attribute__((ext_vector_type(8))) short short8;
typedef __attribute__((ext_vector_type(4))) float f32x4;
typedef __hip_bfloat16 bf16;

__device__ __forceinline__ float b2f(short u) {
    union { unsigned int i; float f; } c;
    c.i = ((unsigned int)(unsigned short)u) << 16;
    return c.f;
}
__device__ __forceinline__ short f2b(float f) {
    bf16 h = __float2bfloat16(f);
    return *reinterpret_cast<short*>(&h);
}

// ---------------- weight fp32 -> bf16 conversion ----------------
__global__ __launch_bounds__(256) void cvt_weights(
        const float* __restrict__ wq, const float* __restrict__ wo,
        const float* __restrict__ w1, const float* __restrict__ w2,
        bf16* __restrict__ oq, bf16* __restrict__ oo,
        bf16* __restrict__ o1, bf16* __restrict__ o2) {
    int i = blockIdx.x * 256 + threadIdx.x;
    if (i < 196608)      oq[i]          = __float2bfloat16(wq[i]);
    else if (i < 262144) oo[i - 196608] = __float2bfloat16(wo[i - 196608]);
    else if (i < 393216) o1[i - 262144] = __float2bfloat16(w1[i - 262144]);
    else                 o2[i - 393216] = __float2bfloat16(w2[i - 393216]);
}

// ---------------- RMSNorm: fp32 in -> bf16 out (1 wave per row) ----------------
__global__ __launch_bounds__(256) void rmsnorm_kernel(const float* __restrict__ x,
        const float* __restrict__ w, bf16* __restrict__ h, int M) {
    int wid = threadIdx.x >> 6, lane = threadIdx.x & 63;
    int row = blockIdx.x * 4 + wid;
    if (row >= M) return;
    const float4 v = reinterpret_cast<const float4*>(x + (size_t)row * DIMD)[lane];
    float ss = v.x * v.x + v.y * v.y + v.z * v.z + v.w * v.w;
    #pragma unroll
    for (int o = 1; o < 64; o <<= 1) ss += __shfl_xor(ss, o, 64);
    float r = rsqrtf(ss * (1.0f / DIMD) + 1e-6f);
    const float4 wv = reinterpret_cast<const float4*>(w)[lane];
    bf16* hp = h + (size_t)row * DIMD + lane * 4;
    hp[0] = __float2bfloat16(v.x * r * wv.x);
    hp[1] = __float2bfloat16(v.y * r * wv.y);
    hp[2] = __float2bfloat16(v.z * r * wv.z);
    hp[3] = __float2bfloat16(v.w * r * wv.w);
}

// ---------------- LDS-staged GEMM C = A * B^T (+bias, epilogue) ----------------
template<int MODE, int BN>
__global__ __launch_bounds__(256) void gemm_lds(
        const bf16* __restrict__ A, const bf16* __restrict__ B,
        const float* __restrict__ bias, const float* __restrict__ resid,
        void* __restrict__ C, int M, int N, int K) {
    constexpr int FN = BN / 32;                 // frags per wave in N
    __shared__ __align__(16) short lA[4 * 128 * 8];
    __shared__ __align__(16) short lB[4 * BN * 8];
    const int tid = threadIdx.x, lane = tid & 63, wid = tid >> 6;
    const int m0 = blockIdx.x * 128;
    const int n0 = blockIdx.y * BN;
    const int wr = wid >> 1, wc = wid & 1;
    const int r = lane & 15, g = lane >> 4;

    f32x4 acc[4][FN];
    #pragma unroll
    for (int i = 0; i < 4; i++)
        #pragma unroll
        for (int j = 0; j < FN; j++) acc[i][j] = (f32x4){0.f, 0.f, 0.f, 0.f};

    for (int k0 = 0; k0 < K; k0 += 32) {
        #pragma unroll
        for (int it = 0; it < 2; ++it) {        // A: 512 cells
            int c = it * 256 + tid;
            int kc = c >> 7, row = c & 127;
            __builtin_amdgcn_global_load_lds(
                (const __attribute__((address_space(1))) void*)(A + (size_t)(m0 + row) * K + k0 + kc * 8),
                (__attribute__((address_space(3))) void*)&lA[c * 8], 16, 0, 0);
        }
        #pragma unroll
        for (int it = 0; it < BN / 64; ++it) {  // B: 4*BN cells
            int c = it * 256 + tid;
            int kc = c / BN, row = c % BN;
            __builtin_amdgcn_global_load_lds(
                (const __attribute__((address_space(1))) void*)(B + (size_t)(n0 + row) * K + k0 + kc * 8),
                (__attribute__((address_space(3))) void*)&lB[c * 8], 16, 0, 0);
        }
        __syncthreads();

        short8 a[4], b[FN];
        #pragma unroll
        for (int mi = 0; mi < 4; mi++)
            a[mi] = *reinterpret_cast<const short8*>(&lA[(g * 128 + wr * 64 + mi * 16 + r) * 8]);
        #pragma unroll
        for (int ni = 0; ni < FN; ni++)
            b[ni] = *reinterpret_cast<const short8*>(&lB[(g * BN + wc * (BN / 2) + ni * 16 + r) * 8]);
        #pragma unroll
        for (int mi = 0; mi < 4; mi++)
            #pragma unroll
            for (int ni = 0; ni < FN; ni++)
                acc[mi][ni] = __builtin_amdgcn_mfma_f32_16x16x32_bf16(a[mi], b[ni], acc[mi][ni], 0, 0, 0);
        __syncthreads();
    }

    const int c0 = lane & 15, r0 = (lane >> 4) * 4;
    #pragma unroll
    for (int mi = 0; mi < 4; mi++) {
        #pragma unroll
        for (int ni = 0; ni < FN; ni++) {
            int col = n0 + wc * (BN / 2) + ni * 16 + c0;
            float bv = bias[col];
            #pragma unroll
            for (int j = 0; j < 4; j++) {
                int row = m0 + wr * 64 + mi * 16 + r0 + j;
                if (row < M) {
                    float v = acc[mi][ni][j] + bv;
                    if (MODE == 2) v = 0.5f * v * (1.0f + erff(v * 0.70710678118654752f));
                    if (MODE == 1) {
                        v += resid[(size_t)row * N + col];
                        reinterpret_cast<float*>(C)[(size_t)row * N + col] = v;
                    } else {
                        reinterpret_cast<bf16*>(C)[(size_t)row * N + col] = __float2bfloat16(v);
                    }
                }
            }
        }
    }
}

// ---------------- V transpose: vT[bh][64 d][VW cols], col = key j + VGUARD ----------------
// Guard columns (j<0 or j>=SEQ) zeroed so PV vector loads never read garbage.
__global__ __launch_bounds__(256) void transpose_v(const short* __restrict__ qkv,
                                                   short* __restrict__ vT) {
    __shared__ short tl[64][72];
    const int tid = threadIdx.x;
    const int jt = blockIdx.x, bh = blockIdx.y;
    const int b = bh >> 2, h = bh & 3;
    const size_t rbase = (size_t)b * SEQ;
    const int cbase = jt * 64;
    #pragma unroll
    for (int it = 0; it < 2; it++) {
        int idx = it * 256 + tid;
        int jj = idx >> 3, dg = (idx & 7) * 8;
        int j = cbase + jj - VGUARD;
        short8 v = (short8){0, 0, 0, 0, 0, 0, 0, 0};
        if (j >= 0 && j < SEQ)
            v = *reinterpret_cast<const short8*>(qkv + (rbase + j) * 768 + 512 + h * 64 + dg);
        *reinterpret_cast<short8*>(&tl[jj][dg]) = v;
    }
    __syncthreads();
    #pragma unroll
    for (int it = 0; it < 2; it++) {
        int idx = it * 256 + tid;
        int d = idx >> 3, jg = (idx & 7) * 8;
        int c = cbase + jg;
        if (c + 8 <= VW) {
            short8 o;
            #pragma unroll
            for (int e = 0; e < 8; e++) o[e] = tl[jg + e][d];
            *reinterpret_cast<short8*>(vT + ((size_t)bh * 64 + d) * VW + c) = o;
        }
    }
}

// ---------------- MFMA banded attention (per-wave 160-slot window + rank-1 global key) ---
// Block = (b,h,qtile64), 4 waves x 16 queries. Wave w: slots t=0..159 -> key
// j = q0w-64+t (invalid masked). Global key 0 handled as rank-1 term when out
// of window (jbase>0). P staged in LDS; V read from pre-transposed global vT.
__global__ __launch_bounds__(256) void attn_band_mfma(const short* __restrict__ qkv,
                                                      const short* __restrict__ vT,
                                                      short* __restrict__ ctx) {
    __shared__ short p_lds[4][16][PSTR];
    const int tid = threadIdx.x, lane = tid & 63, wid = tid >> 6;
    const int qb = blockIdx.x % QBLK;
    const int bh = blockIdx.x / QBLK;
    const int b = bh >> 2, h = bh & 3;
    const size_t rbase = (size_t)b * SEQ;
    const int q0w = qb * 64 + wid * 16;
    const int jbase = q0w - 64;
    const int lrow = lane & 15;
    const int koff = (lane >> 4) * 8;
    const int c0 = lrow, r0 = (lane >> 4) * 4;

    // Q fragments (A: row = lane&15 = q, k = d-slice)
    int qrow = q0w + lrow; if (qrow > SEQ - 1) qrow = SEQ - 1;
    const short* qp = qkv + (rbase + qrow) * 768 + h * 64;
    short8 aq0 = *reinterpret_cast<const short8*>(qp + koff);
    short8 aq1 = *reinterpret_cast<const short8*>(qp + 32 + koff);

    // rank-1 global key: s0[q] = Q[q]·K[0]  (q = lane&15, replicated over groups)
    const short* k0p = qkv + rbase * 768 + 256 + h * 64;
    short8 k0a = *reinterpret_cast<const short8*>(k0p + koff);
    short8 k0b = *reinterpret_cast<const short8*>(k0p + 32 + koff);
    float s0 = 0.f;
    #pragma unroll
    for (int e = 0; e < 8; e++)
        s0 += b2f(aq0[e]) * b2f(k0a[e]) + b2f(aq1[e]) * b2f(k0b[e]);
    s0 += __shfl_xor(s0, 16, 64);
    s0 += __shfl_xor(s0, 32, 64);

    // QK^T over NKB key-blocks
    f32x4 s[NKB];
    #pragma unroll
    for (int n = 0; n < NKB; n++) {
        int j = jbase + n * 16 + lrow;
        int jc = j < 0 ? 0 : (j > SEQ - 1 ? SEQ - 1 : j);
        const short* kp = qkv + (rbase + jc) * 768 + 256 + h * 64;
        short8 bk0 = *reinterpret_cast<const short8*>(kp + koff);
        short8 bk1 = *reinterpret_cast<const short8*>(kp + 32 + koff);
        f32x4 acc = (f32x4){0.f, 0.f, 0.f, 0.f};
        acc = __builtin_amdgcn_mfma_f32_16x16x32_bf16(aq0, bk0, acc, 0, 0, 0);
        acc = __builtin_amdgcn_mfma_f32_16x16x32_bf16(aq1, bk1, acc, 0, 0, 0);
        s[n] = acc;
    }

    // mask + scale (log2 domain); C layout: col=lane&15=slot, row=r0+jj=query
    const float SC = 0.125f * 1.44269504088896340736f;
    const bool g1 = (jbase > 0);            // global key outside window?
    float s0q[4], m4[4];
    #pragma unroll
    for (int jj = 0; jj < 4; jj++) {
        s0q[jj] = __shfl(s0, r0 + jj, 64) * SC;
        m4[jj] = g1 ? s0q[jj] : -1e30f;
    }
    #pragma unroll
    for (int n = 0; n < NKB; n++) {
        int j = jbase + n * 16 + c0;
        bool jv = (j >= 0) && (j < SEQ);
        #pragma unroll
        for (int jj = 0; jj < 4; jj++) {
            int q = q0w + r0 + jj;
            int dd = q - j; if (dd < 0) dd = -dd;
            bool allowed = jv && (dd <= WIN || j == 0);
            float v = allowed ? s[n][jj] * SC : -1e30f;
            s[n][jj] = v;
            m4[jj] = fmaxf(m4[jj], v);
        }
    }
    #pragma unroll
    for (int o = 1; o < 16; o <<= 1) {
        #pragma unroll
        for (int jj = 0; jj < 4; jj++) m4[jj] = fmaxf(m4[jj], __shfl_xor(m4[jj], o, 64));
    }

    // exp, row-sum (seeded with rank-1 p0), write P to LDS
    float p0[4], l4[4];
    #pragma unroll
    for (int jj = 0; jj < 4; jj++) {
        p0[jj] = g1 ? exp2f(s0q[jj] - m4[jj]) : 0.f;
        l4[jj] = p0[jj];
    }
    #pragma unroll
    for (int n = 0; n < NKB; n++) {
        #pragma unroll
        for (int jj = 0; jj < 4; jj++) {
            float p = exp2f(s[n][jj] - m4[jj]);
            l4[jj] += p;
            p_lds[wid][r0 + jj][n * 16 + c0] = f2b(p);
        }
    }
    #pragma unroll
    for (int o = 1; o < 16; o <<= 1) {
        #pragma unroll
        for (int jj = 0; jj < 4; jj++) l4[jj] += __shfl_xor(l4[jj], o, 64);
    }

    __syncthreads();

    // PV: O[16q x 64d] = P[16 x 160] * V^T (B-fragments straight from global vT)
    f32x4 o[4];
    #pragma unroll
    for (int dn = 0; dn < 4; dn++) o[dn] = (f32x4){0.f, 0.f, 0.f, 0.f};
    #pragma unroll
    for (int ks = 0; ks < NKB / 2; ks++) {
        short8 ap = *reinterpret_cast<const short8*>(&p_lds[wid][lrow][ks * 32 + koff]);
        int cc = VGUARD + jbase + ks * 32 + koff;
        #pragma unroll
        for (int dn = 0; dn < 4; dn++) {
            short8 bv = *reinterpret_cast<const short8*>(
                vT + ((size_t)bh * 64 + dn * 16 + lrow) * VW + cc);
            o[dn] = __builtin_amdgcn_mfma_f32_16x16x32_bf16(ap, bv, o[dn], 0, 0, 0);
        }
    }

    // epilogue: add rank-1 term, divide by row sum, store
    #pragma unroll
    for (int jj = 0; jj < 4; jj++) {
        int q = q0w + r0 + jj;
        if (q < SEQ) {
            float rl = 1.0f / l4[jj];
            #pragma unroll
            for (int dn = 0; dn < 4; dn++) {
                float v0 = b2f(qkv[rbase * 768 + 512 + h * 64 + dn * 16 + c0]);
                float val = (o[dn][jj] + p0[jj] * v0) * rl;
                ctx[(rbase + q) * 256 + h * 64 + dn * 16 + c0] = f2b(val);
            }
        }
    }
}

// ---------------- global row q==0: split-K partials ----------------
__global__ __launch_bounds__(256) void attn_global_partial(const bf16* __restrict__ qkv,
                                                           float* __restrict__ part) {
    __shared__ float q_s[64];
    __shared__ float p_s[SPLITK];
    __shared__ float redm[4], redl[4];
    __shared__ float osum[4][64];
    const int tid = threadIdx.x, lane = tid & 63, wid = tid >> 6;
    const int s = blockIdx.x % NSPLIT;
    const int bh = blockIdx.x / NSPLIT;
    const int b = bh >> 2, h = bh & 3;
    const size_t base = (size_t)b * SEQ;
    const int j0 = s * SPLITK;
    const int j1 = (j0 + SPLITK < SEQ) ? (j0 + SPLITK) : SEQ;
    const int nk = j1 - j0;

    if (tid < 64) q_s[tid] = __bfloat162float(qkv[base * 768 + h * 64 + tid]);
    __syncthreads();

    float sc = -1e30f;
    if (tid < nk) {
        const short8* kp = reinterpret_cast<const short8*>(
            reinterpret_cast<const short*>(qkv) + (base + j0 + tid) * 768 + 256 + h * 64);
        float acc = 0.f;
        #pragma unroll
        for (int d8 = 0; d8 < 8; ++d8) {
            short8 kv = kp[d8];
            #pragma unroll
            for (int e = 0; e < 8; ++e) acc += q_s[d8 * 8 + e] * b2f(kv[e]);
        }
        sc = acc * 0.125f;
    }
    float mx = sc;
    #pragma unroll
    for (int o = 1; o < 64; o <<= 1) mx = fmaxf(mx, __shfl_xor(mx, o, 64));
    if (lane == 0) redm[wid] = mx;
    __syncthreads();
    mx = fmaxf(fmaxf(redm[0], redm[1]), fmaxf(redm[2], redm[3]));

    float p = (tid < nk) ? expf(sc - mx) : 0.f;
    if (tid < SPLITK) p_s[tid] = p;
    float l = p;
    #pragma unroll
    for (int o = 1; o < 64; o <<= 1) l += __shfl_xor(l, o, 64);
    if (lane == 0) redl[wid] = l;
    __syncthreads();
    l = redl[0] + redl[1] + redl[2] + redl[3];

    float oa0 = 0.f, oa1 = 0.f;
    for (int i = wid; i < SPLITK; i += 8) {
        float v0 = 0.f, v1 = 0.f;
        if (i < nk)     v0 = __bfloat162float(qkv[(base + j0 + i) * 768 + 512 + h * 64 + lane]);
        if (i + 4 < nk) v1 = __bfloat162float(qkv[(base + j0 + i + 4) * 768 + 512 + h * 64 + lane]);
        oa0 += p_s[i] * v0;
        if (i + 4 < SPLITK) oa1 += p_s[i + 4] * v1;
    }
    osum[wid][lane] = oa0 + oa1;
    __syncthreads();
    if (wid == 0) {
        float o = osum[0][lane] + osum[1][lane] + osum[2][lane] + osum[3][lane];
        float* pp = part + (size_t)(bh * NSPLIT + s) * 66;
        pp[lane] = o;
        if (lane == 0) { pp[64] = mx; pp[65] = l; }
    }
}

// ---------------- global row q==0: combine partials ----------------
__global__ __launch_bounds__(64) void attn_global_combine(const float* __restrict__ part,
                                                          bf16* __restrict__ ctx) {
    const int bh = blockIdx.x;
    const int b = bh >> 2, h = bh & 3;
    const int lane = threadIdx.x;
    float M = -1e30f;
    #pragma unroll
    for (int s = 0; s < NSPLIT; s++) M = fmaxf(M, part[(size_t)(bh * NSPLIT + s) * 66 + 64]);
    float L = 0.f, o = 0.f;
    #pragma unroll
    for (int s = 0; s < NSPLIT; s++) {
        const float* pp = part + (size_t)(bh * NSPLIT + s) * 66;
        float w = expf(pp[64] - M);
        L += pp[65] * w;
        o += pp[lane] * w;
    }
    ctx[(size_t)b * SEQ * 256 + h * 64 + lane] = __float2bfloat16(o / L);
}

extern "C" void kernel_launch(void* const* d_in, const int* in_sizes, int n_in,
                              void* d_out, int out_size, void* d_ws, size_t ws_size,
                              hipStream_t stream) {
    const float* x         = (const float*)d_in[0];
    const float* norm1_w   = (const float*)d_in[1];
    const float* in_proj_w = (const float*)d_in[2];
    const float* in_proj_b = (const float*)d_in[3];
    const float* out_proj_w= (const float*)d_in[4];
    const float* out_proj_b= (const float*)d_in[5];
    const float* norm2_w   = (const float*)d_in[6];
    const float* w1        = (const float*)d_in[7];
    const float* b1        = (const float*)d_in[8];
    const float* w2        = (const float*)d_in[9];
    const float* b2        = (const float*)d_in[10];
    float* out = (float*)d_out;

    const int M = M_ROWS; // 8196
    char* ws = (char*)d_ws;
    size_t off = 0;
    auto take = [&](size_t bytes) {
        char* p = ws + off;
        off = (off + bytes + 255) & ~(size_t)255;
        return p;
    };
    bf16* h_bf   = (bf16*)take((size_t)M_PAD * 256 * 2);
    bf16* qkv_bf = (bf16*)take((size_t)M_PAD * 768 * 2);
    bf16* ctx_bf = (bf16*)take((size_t)M_PAD * 256 * 2);
    float* x1    = (float*)take((size_t)M_PAD * 256 * 4);
    bf16* h2_bf  = (bf16*)take((size_t)M_PAD * 256 * 2);
    bf16* g_bf   = (bf16*)take((size_t)M_PAD * 512 * 2);
    bf16* wq_bf  = (bf16*)take(768 * 256 * 2);
    bf16* wo_bf  = (bf16*)take(256 * 256 * 2);
    bf16* w1_bf  = (bf16*)take(512 * 256 * 2);
    bf16* w2_bf  = (bf16*)take(256 * 512 * 2);
    float* part  = (float*)take((size_t)16 * NSPLIT * 66 * 4);
    short* vT    = (short*)take((size_t)16 * 64 * VW * 2);
    (void)ws_size; (void)in_sizes; (void)n_in; (void)out_size;

    cvt_weights<<<dim3(2048), dim3(256), 0, stream>>>(in_proj_w, out_proj_w, w1, w2,
                                                      wq_bf, wo_bf, w1_bf, w2_bf);
    rmsnorm_kernel<<<dim3((M + 3) / 4), dim3(256), 0, stream>>>(x, norm1_w, h_bf, M);
    gemm_lds<0, 128><<<dim3(65, 6), dim3(256), 0, stream>>>(h_bf, wq_bf, in_proj_b, (const float*)nullptr,
                                                            (void*)qkv_bf, M, 768, 256);
    transpose_v<<<dim3(36, 16), dim3(256), 0, stream>>>((const short*)qkv_bf, vT);
    attn_band_mfma<<<dim3(16 * QBLK), dim3(256), 0, stream>>>((const short*)qkv_bf, vT, (short*)ctx_bf);
    attn_global_partial<<<dim3(16 * NSPLIT), dim3(256), 0, stream>>>(qkv_bf, part);
    attn_global_combine<<<dim3(16), dim3(64), 0, stream>>>(part, ctx_bf);
    gemm_lds<1, 64><<<dim3(65, 4), dim3(256), 0, stream>>>(ctx_bf, wo_bf, out_proj_b, x,
                                                           (void*)x1, M, 256, 256);
    rmsnorm_kernel<<<dim3((M + 3) / 4), dim3(256), 0, stream>>>(x1, norm2_w, h2_bf, M);
    gemm_lds<2, 128><<<dim3(65, 4), dim3(256), 0, stream>>>(h2_bf, w1_bf, b1, (const float*)nullptr,
                                                            (void*)g_bf, M, 512, 256);
    gemm_lds<1, 64><<<dim3(65, 4), dim3(256), 0, stream>>>(g_bf, w2_bf, b2, x1,
                                                           (void*)out, M, 256, 512);
}

// Round 8
// 124.943 us; speedup vs baseline: 4.0172x; 1.1561x over previous
//
#include <hip/hip_runtime.h>
#include <hip/hip_bf16.h>
#include <math.h>

#define BATCH 4
#define SEQ 2049
#define DIMD 256
#define NHEAD 4
#define DH 64
#define WIN 64
#define M_ROWS (BATCH * SEQ) // 8196
#define M_PAD 8320           // 65 * 128, padded rows for unguarded A-tile loads

#define QBLK 33              // 33 query-tiles of 64 covering 2049 rows
#define NKB 10               // per-wave key-blocks of 16 (160 slots)
#define PSTR 168             // p_lds row stride (elems, 16B-aligned)
#define VGUARD 64            // vT zero-guard columns on each side
#define VW 2256              // vT row width: 64 + 2049 + tail guard, mult of 16

#define NSPLIT 33            // 64-key splits for the q==0 global rows (33*64 >= 2049)
#define TBLK 576             // transpose blocks (36 * 16)

typedef __attribute__((ext_vector_type(8))) short short8;
typedef __attribute__((ext_vector_type(4))) float f32x4;
typedef __hip_bfloat16 bf16;

__device__ __forceinline__ float b2f(short u) {
    union { unsigned int i; float f; } c;
    c.i = ((unsigned int)(unsigned short)u) << 16;
    return c.f;
}
__device__ __forceinline__ short f2b(float f) {
    bf16 h = __float2bfloat16(f);
    return *reinterpret_cast<short*>(&h);
}

// ---------------- fused: weight cvt (blocks 0..2047) + RMSNorm1 (blocks 2048..4096) ----
__global__ __launch_bounds__(256) void prep_kernel(
        const float* __restrict__ wq, const float* __restrict__ wo,
        const float* __restrict__ w1, const float* __restrict__ w2,
        bf16* __restrict__ oq, bf16* __restrict__ oo,
        bf16* __restrict__ o1, bf16* __restrict__ o2,
        const float* __restrict__ x, const float* __restrict__ nw,
        bf16* __restrict__ h) {
    const int bi = blockIdx.x, tid = threadIdx.x;
    if (bi < 2048) {
        int i = bi * 256 + tid;
        if (i < 196608)      oq[i]          = __float2bfloat16(wq[i]);
        else if (i < 262144) oo[i - 196608] = __float2bfloat16(wo[i - 196608]);
        else if (i < 393216) o1[i - 262144] = __float2bfloat16(w1[i - 262144]);
        else                 o2[i - 393216] = __float2bfloat16(w2[i - 393216]);
        return;
    }
    int wid = tid >> 6, lane = tid & 63;
    int row = (bi - 2048) * 4 + wid;
    if (row >= M_ROWS) return;
    const float4 v = reinterpret_cast<const float4*>(x + (size_t)row * DIMD)[lane];
    float ss = v.x * v.x + v.y * v.y + v.z * v.z + v.w * v.w;
    #pragma unroll
    for (int o = 1; o < 64; o <<= 1) ss += __shfl_xor(ss, o, 64);
    float r = rsqrtf(ss * (1.0f / DIMD) + 1e-6f);
    const float4 wv = reinterpret_cast<const float4*>(nw)[lane];
    bf16* hp = h + (size_t)row * DIMD + lane * 4;
    hp[0] = __float2bfloat16(v.x * r * wv.x);
    hp[1] = __float2bfloat16(v.y * r * wv.y);
    hp[2] = __float2bfloat16(v.z * r * wv.z);
    hp[3] = __float2bfloat16(v.w * r * wv.w);
}

// ---------------- RMSNorm2 (standalone) ----------------
__global__ __launch_bounds__(256) void rmsnorm_kernel(const float* __restrict__ x,
        const float* __restrict__ w, bf16* __restrict__ h, int M) {
    int wid = threadIdx.x >> 6, lane = threadIdx.x & 63;
    int row = blockIdx.x * 4 + wid;
    if (row >= M) return;
    const float4 v = reinterpret_cast<const float4*>(x + (size_t)row * DIMD)[lane];
    float ss = v.x * v.x + v.y * v.y + v.z * v.z + v.w * v.w;
    #pragma unroll
    for (int o = 1; o < 64; o <<= 1) ss += __shfl_xor(ss, o, 64);
    float r = rsqrtf(ss * (1.0f / DIMD) + 1e-6f);
    const float4 wv = reinterpret_cast<const float4*>(w)[lane];
    bf16* hp = h + (size_t)row * DIMD + lane * 4;
    hp[0] = __float2bfloat16(v.x * r * wv.x);
    hp[1] = __float2bfloat16(v.y * r * wv.y);
    hp[2] = __float2bfloat16(v.z * r * wv.z);
    hp[3] = __float2bfloat16(v.w * r * wv.w);
}

// ---------------- LDS-staged GEMM C = A * B^T (+bias, epilogue), BK=64 ----------------
// BM=128 x BN (128 or 64), 4 waves (2x2), wave tile 64 x BN/2.
// LDS [kc][row][8] (kc-major 16B cells): global_load_lds dest linear-in-lane;
// quarter-wave ds_read_b128 hits 16 consecutive cells (conflict-free).
template<int MODE, int BN>
__global__ __launch_bounds__(256) void gemm_lds(
        const bf16* __restrict__ A, const bf16* __restrict__ B,
        const float* __restrict__ bias, const float* __restrict__ resid,
        void* __restrict__ C, int M, int N, int K) {
    constexpr int FN = BN / 32;
    __shared__ __align__(16) short lA[8 * 128 * 8];
    __shared__ __align__(16) short lB[8 * BN * 8];
    const int tid = threadIdx.x, lane = tid & 63, wid = tid >> 6;
    const int m0 = blockIdx.x * 128;
    const int n0 = blockIdx.y * BN;
    const int wr = wid >> 1, wc = wid & 1;
    const int r = lane & 15, g = lane >> 4;

    f32x4 acc[4][FN];
    #pragma unroll
    for (int i = 0; i < 4; i++)
        #pragma unroll
        for (int j = 0; j < FN; j++) acc[i][j] = (f32x4){0.f, 0.f, 0.f, 0.f};

    for (int k0 = 0; k0 < K; k0 += 64) {
        #pragma unroll
        for (int it = 0; it < 4; ++it) {        // A: 1024 cells
            int c = it * 256 + tid;
            int kc = c >> 7, row = c & 127;
            __builtin_amdgcn_global_load_lds(
                (const __attribute__((address_space(1))) void*)(A + (size_t)(m0 + row) * K + k0 + kc * 8),
                (__attribute__((address_space(3))) void*)&lA[c * 8], 16, 0, 0);
        }
        #pragma unroll
        for (int it = 0; it < BN / 32; ++it) {  // B: 8*BN cells
            int c = it * 256 + tid;
            int kc = c / BN, row = c % BN;
            __builtin_amdgcn_global_load_lds(
                (const __attribute__((address_space(1))) void*)(B + (size_t)(n0 + row) * K + k0 + kc * 8),
                (__attribute__((address_space(3))) void*)&lB[c * 8], 16, 0, 0);
        }
        __syncthreads();

        #pragma unroll
        for (int kk = 0; kk < 2; kk++) {
            short8 a[4], b[FN];
            #pragma unroll
            for (int mi = 0; mi < 4; mi++)
                a[mi] = *reinterpret_cast<const short8*>(&lA[((kk * 4 + g) * 128 + wr * 64 + mi * 16 + r) * 8]);
            #pragma unroll
            for (int ni = 0; ni < FN; ni++)
                b[ni] = *reinterpret_cast<const short8*>(&lB[((kk * 4 + g) * BN + wc * (BN / 2) + ni * 16 + r) * 8]);
            #pragma unroll
            for (int mi = 0; mi < 4; mi++)
                #pragma unroll
                for (int ni = 0; ni < FN; ni++)
                    acc[mi][ni] = __builtin_amdgcn_mfma_f32_16x16x32_bf16(a[mi], b[ni], acc[mi][ni], 0, 0, 0);
        }
        __syncthreads();
    }

    const int c0 = lane & 15, r0 = (lane >> 4) * 4;
    #pragma unroll
    for (int mi = 0; mi < 4; mi++) {
        #pragma unroll
        for (int ni = 0; ni < FN; ni++) {
            int col = n0 + wc * (BN / 2) + ni * 16 + c0;
            float bv = bias[col];
            #pragma unroll
            for (int j = 0; j < 4; j++) {
                int row = m0 + wr * 64 + mi * 16 + r0 + j;
                if (row < M) {
                    float v = acc[mi][ni][j] + bv;
                    if (MODE == 2) v = 0.5f * v * (1.0f + erff(v * 0.70710678118654752f));
                    if (MODE == 1) {
                        v += resid[(size_t)row * N + col];
                        reinterpret_cast<float*>(C)[(size_t)row * N + col] = v;
                    } else {
                        reinterpret_cast<bf16*>(C)[(size_t)row * N + col] = __float2bfloat16(v);
                    }
                }
            }
        }
    }
}

// ---------------- fused: V transpose (blocks 0..575) + q==0 split-K partials ----------
__global__ __launch_bounds__(256) void trans_partial(const short* __restrict__ qkv,
                                                     short* __restrict__ vT,
                                                     float* __restrict__ part) {
    const int tid = threadIdx.x;
    if (blockIdx.x < TBLK) {
        // ---- transpose: vT[bh][64 d][VW], col = key j + VGUARD (guards zeroed) ----
        __shared__ short tl[64][72];
        const int jt = blockIdx.x % 36, bh = blockIdx.x / 36;
        const int b = bh >> 2, h = bh & 3;
        const size_t rbase = (size_t)b * SEQ;
        const int cbase = jt * 64;
        #pragma unroll
        for (int it = 0; it < 2; it++) {
            int idx = it * 256 + tid;
            int jj = idx >> 3, dg = (idx & 7) * 8;
            int j = cbase + jj - VGUARD;
            short8 v = (short8){0, 0, 0, 0, 0, 0, 0, 0};
            if (j >= 0 && j < SEQ)
                v = *reinterpret_cast<const short8*>(qkv + (rbase + j) * 768 + 512 + h * 64 + dg);
            *reinterpret_cast<short8*>(&tl[jj][dg]) = v;
        }
        __syncthreads();
        #pragma unroll
        for (int it = 0; it < 2; it++) {
            int idx = it * 256 + tid;
            int d = idx >> 3, jg = (idx & 7) * 8;
            int c = cbase + jg;
            if (c + 8 <= VW) {
                short8 o;
                #pragma unroll
                for (int e = 0; e < 8; e++) o[e] = tl[jg + e][d];
                *reinterpret_cast<short8*>(vT + ((size_t)bh * 64 + d) * VW + c) = o;
            }
        }
        return;
    }
    // ---- partial: (bh, split s) over keys [s*64, s*64+64) ----
    __shared__ float q_s[64];
    __shared__ float p_s[64];
    __shared__ float meta[2];
    __shared__ float osum[4][64];
    const int idx = blockIdx.x - TBLK;
    const int bh = idx / NSPLIT, s = idx % NSPLIT;
    const int b = bh >> 2, h = bh & 3;
    const size_t base = (size_t)b * SEQ;
    const int j0 = s * 64;
    const int lane = tid & 63, wid = tid >> 6;

    if (tid < 64) q_s[tid] = b2f(qkv[base * 768 + h * 64 + tid]);
    __syncthreads();

    if (wid == 0) {
        int j = j0 + lane;
        float sc = -1e30f;
        if (j < SEQ) {
            const short8* kp = reinterpret_cast<const short8*>(qkv + (base + j) * 768 + 256 + h * 64);
            float acc = 0.f;
            #pragma unroll
            for (int d8 = 0; d8 < 8; ++d8) {
                short8 kv = kp[d8];
                #pragma unroll
                for (int e = 0; e < 8; ++e) acc += q_s[d8 * 8 + e] * b2f(kv[e]);
            }
            sc = acc * 0.125f;
        }
        float mx = sc;
        #pragma unroll
        for (int o = 1; o < 64; o <<= 1) mx = fmaxf(mx, __shfl_xor(mx, o, 64));
        float p = (j < SEQ) ? expf(sc - mx) : 0.f;
        p_s[lane] = p;
        float l = p;
        #pragma unroll
        for (int o = 1; o < 64; o <<= 1) l += __shfl_xor(l, o, 64);
        if (lane == 0) { meta[0] = mx; meta[1] = l; }
    }
    __syncthreads();

    float oa = 0.f;
    #pragma unroll
    for (int i0 = 0; i0 < 16; i0++) {
        int i = wid + i0 * 4;
        if (j0 + i < SEQ) oa += p_s[i] * b2f(qkv[(base + j0 + i) * 768 + 512 + h * 64 + lane]);
    }
    osum[wid][lane] = oa;
    __syncthreads();
    if (wid == 0) {
        float o = osum[0][lane] + osum[1][lane] + osum[2][lane] + osum[3][lane];
        float* pp = part + (size_t)(bh * NSPLIT + s) * 66;
        pp[lane] = o;
        if (lane == 0) { pp[64] = meta[0]; pp[65] = meta[1]; }
    }
}

// ---------------- MFMA banded attention + fused q==0 combine (qb==0 blocks) ----------
__global__ __launch_bounds__(256) void attn_band_mfma(const short* __restrict__ qkv,
                                                      const short* __restrict__ vT,
                                                      const float* __restrict__ part,
                                                      short* __restrict__ ctx) {
    __shared__ short p_lds[4][16][PSTR];
    const int tid = threadIdx.x, lane = tid & 63, wid = tid >> 6;
    const int qb = blockIdx.x % QBLK;
    const int bh = blockIdx.x / QBLK;
    const int b = bh >> 2, h = bh & 3;
    const size_t rbase = (size_t)b * SEQ;
    const int q0w = qb * 64 + wid * 16;
    const int jbase = q0w - 64;
    const int lrow = lane & 15;
    const int koff = (lane >> 4) * 8;
    const int c0 = lrow, r0 = (lane >> 4) * 4;

    int qrow = q0w + lrow; if (qrow > SEQ - 1) qrow = SEQ - 1;
    const short* qp = qkv + (rbase + qrow) * 768 + h * 64;
    short8 aq0 = *reinterpret_cast<const short8*>(qp + koff);
    short8 aq1 = *reinterpret_cast<const short8*>(qp + 32 + koff);

    // rank-1 global key: s0[q] = Q[q]·K[0]
    const short* k0p = qkv + rbase * 768 + 256 + h * 64;
    short8 k0a = *reinterpret_cast<const short8*>(k0p + koff);
    short8 k0b = *reinterpret_cast<const short8*>(k0p + 32 + koff);
    float s0 = 0.f;
    #pragma unroll
    for (int e = 0; e < 8; e++)
        s0 += b2f(aq0[e]) * b2f(k0a[e]) + b2f(aq1[e]) * b2f(k0b[e]);
    s0 += __shfl_xor(s0, 16, 64);
    s0 += __shfl_xor(s0, 32, 64);

    f32x4 s[NKB];
    #pragma unroll
    for (int n = 0; n < NKB; n++) {
        int j = jbase + n * 16 + lrow;
        int jc = j < 0 ? 0 : (j > SEQ - 1 ? SEQ - 1 : j);
        const short* kp = qkv + (rbase + jc) * 768 + 256 + h * 64;
        short8 bk0 = *reinterpret_cast<const short8*>(kp + koff);
        short8 bk1 = *reinterpret_cast<const short8*>(kp + 32 + koff);
        f32x4 acc = (f32x4){0.f, 0.f, 0.f, 0.f};
        acc = __builtin_amdgcn_mfma_f32_16x16x32_bf16(aq0, bk0, acc, 0, 0, 0);
        acc = __builtin_amdgcn_mfma_f32_16x16x32_bf16(aq1, bk1, acc, 0, 0, 0);
        s[n] = acc;
    }

    const float SC = 0.125f * 1.44269504088896340736f;
    const bool g1 = (jbase > 0);
    float s0q[4], m4[4];
    #pragma unroll
    for (int jj = 0; jj < 4; jj++) {
        s0q[jj] = __shfl(s0, r0 + jj, 64) * SC;
        m4[jj] = g1 ? s0q[jj] : -1e30f;
    }
    #pragma unroll
    for (int n = 0; n < NKB; n++) {
        int j = jbase + n * 16 + c0;
        bool jv = (j >= 0) && (j < SEQ);
        #pragma unroll
        for (int jj = 0; jj < 4; jj++) {
            int q = q0w + r0 + jj;
            int dd = q - j; if (dd < 0) dd = -dd;
            bool allowed = jv && (dd <= WIN || j == 0);
            float v = allowed ? s[n][jj] * SC : -1e30f;
            s[n][jj] = v;
            m4[jj] = fmaxf(m4[jj], v);
        }
    }
    #pragma unroll
    for (int o = 1; o < 16; o <<= 1) {
        #pragma unroll
        for (int jj = 0; jj < 4; jj++) m4[jj] = fmaxf(m4[jj], __shfl_xor(m4[jj], o, 64));
    }

    float p0[4], l4[4];
    #pragma unroll
    for (int jj = 0; jj < 4; jj++) {
        p0[jj] = g1 ? exp2f(s0q[jj] - m4[jj]) : 0.f;
        l4[jj] = p0[jj];
    }
    #pragma unroll
    for (int n = 0; n < NKB; n++) {
        #pragma unroll
        for (int jj = 0; jj < 4; jj++) {
            float p = exp2f(s[n][jj] - m4[jj]);
            l4[jj] += p;
            p_lds[wid][r0 + jj][n * 16 + c0] = f2b(p);
        }
    }
    #pragma unroll
    for (int o = 1; o < 16; o <<= 1) {
        #pragma unroll
        for (int jj = 0; jj < 4; jj++) l4[jj] += __shfl_xor(l4[jj], o, 64);
    }

    __syncthreads();

    f32x4 o[4];
    #pragma unroll
    for (int dn = 0; dn < 4; dn++) o[dn] = (f32x4){0.f, 0.f, 0.f, 0.f};
    #pragma unroll
    for (int ks = 0; ks < NKB / 2; ks++) {
        short8 ap = *reinterpret_cast<const short8*>(&p_lds[wid][lrow][ks * 32 + koff]);
        int cc = VGUARD + jbase + ks * 32 + koff;
        #pragma unroll
        for (int dn = 0; dn < 4; dn++) {
            short8 bv = *reinterpret_cast<const short8*>(
                vT + ((size_t)bh * 64 + dn * 16 + lrow) * VW + cc);
            o[dn] = __builtin_amdgcn_mfma_f32_16x16x32_bf16(ap, bv, o[dn], 0, 0, 0);
        }
    }

    // epilogue: rank-1 term + divide; skip q==0 (combined row written below)
    #pragma unroll
    for (int jj = 0; jj < 4; jj++) {
        int q = q0w + r0 + jj;
        if (q >= 1 && q < SEQ) {
            float rl = 1.0f / l4[jj];
            #pragma unroll
            for (int dn = 0; dn < 4; dn++) {
                float v0 = b2f(qkv[rbase * 768 + 512 + h * 64 + dn * 16 + c0]);
                float val = (o[dn][jj] + p0[jj] * v0) * rl;
                ctx[(rbase + q) * 256 + h * 64 + dn * 16 + c0] = f2b(val);
            }
        }
    }

    // ---- fused combine for q==0 (part[] written by previous kernel) ----
    if (qb == 0) {
        __syncthreads();
        if (wid == 0) {
            float m = (lane < NSPLIT) ? part[(size_t)(bh * NSPLIT + lane) * 66 + 64] : -1e30f;
            #pragma unroll
            for (int o2 = 1; o2 < 64; o2 <<= 1) m = fmaxf(m, __shfl_xor(m, o2, 64));
            float L = 0.f, ov = 0.f;
            for (int sp = 0; sp < NSPLIT; sp++) {
                const float* pp = part + (size_t)(bh * NSPLIT + sp) * 66;
                float w = expf(pp[64] - m);
                L += pp[65] * w;
                ov += pp[lane] * w;
            }
            ctx[rbase * 256 + h * 64 + lane] = f2b(ov / L);
        }
    }
}

extern "C" void kernel_launch(void* const* d_in, const int* in_sizes, int n_in,
                              void* d_out, int out_size, void* d_ws, size_t ws_size,
                              hipStream_t stream) {
    const float* x         = (const float*)d_in[0];
    const float* norm1_w   = (const float*)d_in[1];
    const float* in_proj_w = (const float*)d_in[2];
    const float* in_proj_b = (const float*)d_in[3];
    const float* out_proj_w= (const float*)d_in[4];
    const float* out_proj_b= (const float*)d_in[5];
    const float* norm2_w   = (const float*)d_in[6];
    const float* w1        = (const float*)d_in[7];
    const float* b1        = (const float*)d_in[8];
    const float* w2        = (const float*)d_in[9];
    const float* b2        = (const float*)d_in[10];
    float* out = (float*)d_out;

    const int M = M_ROWS; // 8196
    char* ws = (char*)d_ws;
    size_t off = 0;
    auto take = [&](size_t bytes) {
        char* p = ws + off;
        off = (off + bytes + 255) & ~(size_t)255;
        return p;
    };
    bf16* h_bf   = (bf16*)take((size_t)M_PAD * 256 * 2);
    bf16* qkv_bf = (bf16*)take((size_t)M_PAD * 768 * 2);
    bf16* ctx_bf = (bf16*)take((size_t)M_PAD * 256 * 2);
    float* x1    = (float*)take((size_t)M_PAD * 256 * 4);
    bf16* h2_bf  = (bf16*)take((size_t)M_PAD * 256 * 2);
    bf16* g_bf   = (bf16*)take((size_t)M_PAD * 512 * 2);
    bf16* wq_bf  = (bf16*)take(768 * 256 * 2);
    bf16* wo_bf  = (bf16*)take(256 * 256 * 2);
    bf16* w1_bf  = (bf16*)take(512 * 256 * 2);
    bf16* w2_bf  = (bf16*)take(256 * 512 * 2);
    float* part  = (float*)take((size_t)16 * NSPLIT * 66 * 4);
    short* vT    = (short*)take((size_t)16 * 64 * VW * 2);
    (void)ws_size; (void)in_sizes; (void)n_in; (void)out_size;

    prep_kernel<<<dim3(2048 + 2049), dim3(256), 0, stream>>>(
        in_proj_w, out_proj_w, w1, w2, wq_bf, wo_bf, w1_bf, w2_bf, x, norm1_w, h_bf);
    gemm_lds<0, 128><<<dim3(65, 6), dim3(256), 0, stream>>>(h_bf, wq_bf, in_proj_b, (const float*)nullptr,
                                                            (void*)qkv_bf, M, 768, 256);
    trans_partial<<<dim3(TBLK + 16 * NSPLIT), dim3(256), 0, stream>>>(
        (const short*)qkv_bf, vT, part);
    attn_band_mfma<<<dim3(16 * QBLK), dim3(256), 0, stream>>>(
        (const short*)qkv_bf, vT, part, (short*)ctx_bf);
    gemm_lds<1, 64><<<dim3(65, 4), dim3(256), 0, stream>>>(ctx_bf, wo_bf, out_proj_b, x,
                                                           (void*)x1, M, 256, 256);
    rmsnorm_kernel<<<dim3((M + 3) / 4), dim3(256), 0, stream>>>(x1, norm2_w, h2_bf, M);
    gemm_lds<2, 128><<<dim3(65, 4), dim3(256), 0, stream>>>(h2_bf, w1_bf, b1, (const float*)nullptr,
                                                            (void*)g_bf, M, 512, 256);
    gemm_lds<1, 64><<<dim3(65, 4), dim3(256), 0, stream>>>(g_bf, w2_bf, b2, x1,
                                                           (void*)out, M, 256, 512);
}